// Round 13
// baseline (654.656 us; speedup 1.0000x reference)
//
#include <hip/hip_runtime.h>
#include <hip/hip_bf16.h>
#include <cstdint>
#include <cstddef>

#define HWPIX 65536
#define IMGW 256
#define CDIM 192
#define C3 576
#define NBATCH 4
#define NHEADS 8
#define CPH 24
#define KP 104   // padded K pitch (bf16 elems) for MFMA LDS tiles

using bf16 = __hip_bfloat16;
typedef __attribute__((ext_vector_type(8))) short short8;
typedef __attribute__((ext_vector_type(4))) float f32x4;
typedef unsigned int u32;
typedef unsigned short u16;

__device__ __forceinline__ float b2f(bf16 v) { return __bfloat162float(v); }
__device__ __forceinline__ bf16 f2b(float v) { return __float2bfloat16(v); }
__device__ __forceinline__ float bu2f(u16 h) { return __uint_as_float((u32)h << 16); }
__device__ __forceinline__ u16 f2bu(float x) {
    bf16 h = __float2bfloat16(x);
    return *reinterpret_cast<u16*>(&h);
}
__device__ __forceinline__ u32 pack2(float a, float b) {
    return (u32)f2bu(a) | ((u32)f2bu(b) << 16);
}

// ---------------------------------------------------------------------------
// Convert weights f32 -> bf16 (u16).
// ---------------------------------------------------------------------------
__global__ __launch_bounds__(256) void prep_weights(
    const float* __restrict__ W, u16* __restrict__ Wb, int n)
{
    int i = blockIdx.x * 256 + threadIdx.x;
    if (i < n) Wb[i] = f2bu(W[i]);
}

// ---------------------------------------------------------------------------
// X f32 [b][k][p] -> Xt bf16 [b][p][k]  (one-time transpose+convert).
// ---------------------------------------------------------------------------
__global__ __launch_bounds__(256) void xprep_kernel(
    const float* __restrict__ X, u16* __restrict__ Xt)
{
    __shared__ float sX[CDIM * 68];
    const int b  = blockIdx.y;
    const int p0 = blockIdx.x * 64;
    const int tid = threadIdx.x;

#pragma unroll
    for (int i = 0; i < 12; ++i) {
        const int idx = tid + i * 256;        // 0..3071 float4s
        const int p4 = idx & 15, k = idx >> 4;
        const float4 v = *reinterpret_cast<const float4*>(
            X + ((size_t)b * CDIM + k) * HWPIX + p0 + p4 * 4);
        *reinterpret_cast<float4*>(&sX[k * 68 + p4 * 4]) = v;
    }
    __syncthreads();

    const int p = tid >> 2;          // 0..63
    const int seg = tid & 3;         // 0..3 (6 k-blocks each)
    u16* dst = Xt + ((size_t)b * HWPIX + p0 + p) * CDIM;
#pragma unroll
    for (int s = 0; s < 6; ++s) {
        const int blk = seg * 6 + s; // 0..23, 8 k each
        float f[8];
#pragma unroll
        for (int j = 0; j < 8; ++j) f[j] = sX[(blk * 8 + j) * 68 + p];
        uint4 ov;
        ov.x = pack2(f[0], f[1]);
        ov.y = pack2(f[2], f[3]);
        ov.z = pack2(f[4], f[5]);
        ov.w = pack2(f[6], f[7]);
        *reinterpret_cast<uint4*>(dst + blk * 8) = ov;
    }
}

// ---------------------------------------------------------------------------
// Generic 64xCout-tile x 128p MFMA GEMM reading row-major [p][k] bf16 input.
// (R10 conv_qkv structure — the proven 154us variant.)
// Stages A (weights) + B (input rows) as pure uint4 copies into KP-padded
// LDS; 2 chunks of K=96; epilogue via stride-132 LDS tile.
// ---------------------------------------------------------------------------
__device__ __forceinline__ void chunk_mfma(
    const u16* sA, const u16* sB, int r, int hk, int wave, f32x4 (&acc)[4][2])
{
#pragma unroll
    for (int ks = 0; ks < 3; ++ks) {
        const int kof = ks * 32 + hk * 8;
        const u16* pA = &sA[r * KP + kof];
        const u16* pB = &sB[(wave * 32 + r) * KP + kof];
        const short8 a0 = *reinterpret_cast<const short8*>(pA);
        const short8 a1 = *reinterpret_cast<const short8*>(pA + 16 * KP);
        const short8 a2 = *reinterpret_cast<const short8*>(pA + 32 * KP);
        const short8 a3 = *reinterpret_cast<const short8*>(pA + 48 * KP);
        const short8 b0 = *reinterpret_cast<const short8*>(pB);
        const short8 b1 = *reinterpret_cast<const short8*>(pB + 16 * KP);
        acc[0][0] = __builtin_amdgcn_mfma_f32_16x16x32_bf16(a0, b0, acc[0][0], 0, 0, 0);
        acc[1][0] = __builtin_amdgcn_mfma_f32_16x16x32_bf16(a1, b0, acc[1][0], 0, 0, 0);
        acc[2][0] = __builtin_amdgcn_mfma_f32_16x16x32_bf16(a2, b0, acc[2][0], 0, 0, 0);
        acc[3][0] = __builtin_amdgcn_mfma_f32_16x16x32_bf16(a3, b0, acc[3][0], 0, 0, 0);
        acc[0][1] = __builtin_amdgcn_mfma_f32_16x16x32_bf16(a0, b1, acc[0][1], 0, 0, 0);
        acc[1][1] = __builtin_amdgcn_mfma_f32_16x16x32_bf16(a1, b1, acc[1][1], 0, 0, 0);
        acc[2][1] = __builtin_amdgcn_mfma_f32_16x16x32_bf16(a2, b1, acc[2][1], 0, 0, 0);
        acc[3][1] = __builtin_amdgcn_mfma_f32_16x16x32_bf16(a3, b1, acc[3][1], 0, 0, 0);
    }
}

// ---------------------------------------------------------------------------
// qkv 1x1 conv (exact R10 structure): Y bf16 [b][co][p].
// ---------------------------------------------------------------------------
__global__ __launch_bounds__(256, 4) void conv_qkv_mfma(
    const u16* __restrict__ Xt, const u16* __restrict__ Wb,
    const float* __restrict__ bias, bf16* __restrict__ Y)
{
    __shared__ alignas(16) u16 sA[64 * KP];
    __shared__ alignas(16) u16 sB[128 * KP];
    __shared__ float sBias[64];

    int lin = blockIdx.x;
    lin = (lin & 7) * (18432 / 8) + (lin >> 3);
    const int co_t = lin % 9;
    const int rest = lin / 9;
    const int p_t = rest & 511;
    const int b   = rest >> 9;
    const int co0 = co_t * 64;
    const int p0  = p_t * 128;

    const int tid  = threadIdx.x;
    const int wave = tid >> 6;
    const int lane = tid & 63;
    const int r  = lane & 15;
    const int hk = lane >> 4;

    if (tid < 64) sBias[tid] = bias[co0 + tid];

    f32x4 acc[4][2];
#pragma unroll
    for (int i = 0; i < 4; ++i)
#pragma unroll
        for (int j = 0; j < 2; ++j) acc[i][j] = (f32x4){0.f, 0.f, 0.f, 0.f};

#pragma unroll
    for (int c = 0; c < 2; ++c) {
        {
            int idx = tid;
#pragma unroll
            for (int i = 0; i < 3; ++i, idx += 256) {
                const int row = idx / 12, cv = idx % 12;
                const uint4 v = *reinterpret_cast<const uint4*>(
                    Wb + (size_t)(co0 + row) * CDIM + c * 96 + cv * 8);
                *reinterpret_cast<uint4*>(&sA[row * KP + cv * 8]) = v;
            }
        }
        {
            int idx = tid;
#pragma unroll
            for (int i = 0; i < 6; ++i, idx += 256) {
                const int row = idx / 12, cv = idx % 12;
                const uint4 v = *reinterpret_cast<const uint4*>(
                    Xt + ((size_t)b * HWPIX + p0 + row) * CDIM + c * 96 + cv * 8);
                *reinterpret_cast<uint4*>(&sB[row * KP + cv * 8]) = v;
            }
        }
        __syncthreads();
        chunk_mfma(sA, sB, r, hk, wave, acc);
        __syncthreads();
    }

#define OS2 132
    u16* sOut = sB;
#pragma unroll
    for (int mf = 0; mf < 4; ++mf) {
#pragma unroll
        for (int j = 0; j < 4; ++j) {
            const int row = mf * 16 + hk * 4 + j;
            const float bs = sBias[row];
            sOut[row * OS2 + wave * 32 + r]      = f2bu(acc[mf][0][j] + bs);
            sOut[row * OS2 + wave * 32 + r + 16] = f2bu(acc[mf][1][j] + bs);
        }
    }
    __syncthreads();
#pragma unroll
    for (int i = 0; i < 4; ++i) {
        const int idx = tid + i * 256;
        const int row = idx >> 4, cq = idx & 15;
        const u16* src = &sOut[row * OS2 + cq * 8];
        const uint2 lo = *reinterpret_cast<const uint2*>(src);
        const uint2 hi = *reinterpret_cast<const uint2*>(src + 4);
        uint4 v = {lo.x, lo.y, hi.x, hi.y};
        *reinterpret_cast<uint4*>(
            &Y[((size_t)b * C3 + co0 + row) * HWPIX + p0 + cq * 8]) = v;
    }
}

// ---------------------------------------------------------------------------
// proj 1x1 conv — NOW reads pixel-major osum_t [b][p][192] bf16 (written by
// local_attn), so staging is pure uint4 copy (same proven structure as qkv).
// Output f32 [b][co][p] direct stores.
// ---------------------------------------------------------------------------
__global__ __launch_bounds__(256, 4) void conv_proj_mfma(
    const u16* __restrict__ Ot, const u16* __restrict__ Wb,
    const float* __restrict__ bias, float* __restrict__ Y)
{
    __shared__ alignas(16) u16 sA[64 * KP];
    __shared__ alignas(16) u16 sB[128 * KP];
    __shared__ float sBias[64];

    int lin = blockIdx.x;                       // nwg = 6144
    lin = (lin & 7) * (6144 / 8) + (lin >> 3);
    const int co_t = lin % 3;
    const int rest = lin / 3;
    const int p_t = rest & 511;
    const int b   = rest >> 9;
    const int co0 = co_t * 64;
    const int p0  = p_t * 128;

    const int tid  = threadIdx.x;
    const int wave = tid >> 6;
    const int lane = tid & 63;
    const int r  = lane & 15;
    const int hk = lane >> 4;

    if (tid < 64) sBias[tid] = bias[co0 + tid];

    f32x4 acc[4][2];
#pragma unroll
    for (int i = 0; i < 4; ++i)
#pragma unroll
        for (int j = 0; j < 2; ++j) acc[i][j] = (f32x4){0.f, 0.f, 0.f, 0.f};

#pragma unroll
    for (int c = 0; c < 2; ++c) {
        {
            int idx = tid;
#pragma unroll
            for (int i = 0; i < 3; ++i, idx += 256) {
                const int row = idx / 12, cv = idx % 12;
                const uint4 v = *reinterpret_cast<const uint4*>(
                    Wb + (size_t)(co0 + row) * CDIM + c * 96 + cv * 8);
                *reinterpret_cast<uint4*>(&sA[row * KP + cv * 8]) = v;
            }
        }
        {
            int idx = tid;
#pragma unroll
            for (int i = 0; i < 6; ++i, idx += 256) {
                const int row = idx / 12, cv = idx % 12;
                const uint4 v = *reinterpret_cast<const uint4*>(
                    Ot + ((size_t)b * HWPIX + p0 + row) * CDIM + c * 96 + cv * 8);
                *reinterpret_cast<uint4*>(&sB[row * KP + cv * 8]) = v;
            }
        }
        __syncthreads();
        chunk_mfma(sA, sB, r, hk, wave, acc);
        __syncthreads();
    }

    // epilogue: f32 stores, 16-lane groups are 64B contiguous
#pragma unroll
    for (int mf = 0; mf < 4; ++mf) {
#pragma unroll
        for (int j = 0; j < 4; ++j) {
            const int co = co0 + mf * 16 + hk * 4 + j;
            const float bs = sBias[mf * 16 + hk * 4 + j];
            const size_t base = ((size_t)b * CDIM + co) * HWPIX + p0 + wave * 32 + r;
            Y[base]      = acc[mf][0][j] + bs;
            Y[base + 16] = acc[mf][1][j] + bs;
        }
    }
}

// ---------------------------------------------------------------------------
// Depthwise 3x3 SAME conv — 32-row tiles (unchanged).
// ---------------------------------------------------------------------------
__global__ __launch_bounds__(256) void dwconv_kernel(
    const bf16* __restrict__ In, const float* __restrict__ Wd,
    const float* __restrict__ bd, bf16* __restrict__ Out)
{
    __shared__ alignas(16) u16 sIn[34 * 256];   // 17408 B
    const int bc = blockIdx.y;            // b*576 + c
    const int c = bc % C3;
    const size_t base = (size_t)bc * HWPIX;
    const int r0 = blockIdx.x * 32;
    const int tid = threadIdx.x;

    for (int idx = tid; idx < 34 * 32; idx += 256) {
        const int lr = idx >> 5, ch = idx & 31;
        const int gr = r0 + lr - 1;
        uint4 v = {0u, 0u, 0u, 0u};
        if ((unsigned)gr < IMGW)
            v = *reinterpret_cast<const uint4*>(&In[base + (size_t)gr * IMGW + ch * 8]);
        *reinterpret_cast<uint4*>(&sIn[lr * 256 + ch * 8]) = v;
    }
    __syncthreads();

    float wg[9];
#pragma unroll
    for (int t = 0; t < 9; ++t) wg[t] = Wd[c * 9 + t];

    const int rr  = tid >> 5;             // 0..7
    const int px0 = (tid & 31) * 8;
    const float bias = bd[c];

#pragma unroll
    for (int kk = 0; kk < 4; ++kk) {
        const int orow = rr + kk * 8;     // output row within tile 0..31
        float acc[8];
#pragma unroll
        for (int j = 0; j < 8; ++j) acc[j] = bias;

#pragma unroll
        for (int dy = 0; dy < 3; ++dy) {
            const u16* rp = &sIn[(orow + dy) * 256];
            const short8 mv = *reinterpret_cast<const short8*>(&rp[px0]);
            float m[8];
#pragma unroll
            for (int j = 0; j < 8; ++j) m[j] = bu2f((u16)mv[j]);
            const float lft = (px0 > 0) ? bu2f(rp[px0 - 1]) : 0.f;
            const float rgt = (px0 + 8 < 256) ? bu2f(rp[px0 + 8]) : 0.f;
            const float w0 = wg[dy * 3], w1 = wg[dy * 3 + 1], w2 = wg[dy * 3 + 2];

            acc[0] = fmaf(w0, lft, acc[0]);
            acc[0] = fmaf(w1, m[0], acc[0]);
            acc[0] = fmaf(w2, m[1], acc[0]);
#pragma unroll
            for (int j = 1; j < 7; ++j) {
                acc[j] = fmaf(w0, m[j - 1], acc[j]);
                acc[j] = fmaf(w1, m[j], acc[j]);
                acc[j] = fmaf(w2, m[j + 1], acc[j]);
            }
            acc[7] = fmaf(w0, m[6], acc[7]);
            acc[7] = fmaf(w1, m[7], acc[7]);
            acc[7] = fmaf(w2, rgt, acc[7]);
        }

        uint4 ov;
        ov.x = pack2(acc[0], acc[1]);
        ov.y = pack2(acc[2], acc[3]);
        ov.z = pack2(acc[4], acc[5]);
        ov.w = pack2(acc[6], acc[7]);
        *reinterpret_cast<uint4*>(&Out[base + (size_t)(r0 + orow) * IMGW + px0]) = ov;
    }
}

// ---------------------------------------------------------------------------
// Local (windowed 8x8) channel attention + fused global apply.
// R13: epilogue writes PIXEL-MAJOR osum_t [b][p][192] bf16 — per (b,head)
// block writes its 24-c slice (48B contiguous, 16B-aligned) per pixel.
// Enables pure-copy staging in proj. setprio kept.
// ---------------------------------------------------------------------------
#define CS 328          // c-row stride (u16)
#define PS 40           // row stride (u16) for sP
#define OS3 28          // pixel-major out tile stride (u16)

__global__ __launch_bounds__(256, 3) void local_attn_kernel(
    const bf16* __restrict__ QKV, const float* __restrict__ temp,
    const float* __restrict__ Ag, u16* __restrict__ Ot)
{
    __shared__ alignas(16) u16 sMem[3 * 24 * CS];
    __shared__ float snq[4 * 32], snk[4 * 32];
    __shared__ float sAg[576];
    u16* const sQ = sMem;
    u16* const sK = sMem + 24 * CS;
    u16* const sV = sMem + 48 * CS;
    u16* const sP = sQ;     // overlay: sQ dead after Gram (barrier-protected)
    u16* const sO = sK;     // overlay: sK dead after Gram (256*28=7168 <= 7872)

    const int wy    = blockIdx.x >> 3;
    const int strip = blockIdx.x & 7;
    const int head  = blockIdx.y;
    const int b     = blockIdx.z;
    const int x0    = strip * 32;
    const int tid   = threadIdx.x;
    const int w     = tid >> 6;
    const int lane  = tid & 63;
    const int r     = lane & 15;
    const int hk    = lane >> 4;

    {
        const float* Asrc = Ag + ((size_t)(b * NHEADS + head)) * 576;
        for (int idx = tid; idx < 576; idx += 256) sAg[idx] = Asrc[idx];
    }

#pragma unroll
    for (int i = 0; i < 9; ++i) {
        const int idx = tid + i * 256;
        const int tensor = idx / 768;
        const int rem = idx - tensor * 768;
        const int c  = rem >> 5;
        const int rw = (rem >> 2) & 7;
        const int ch = rem & 3;
        const size_t g = ((size_t)b * C3 + tensor * CDIM + head * CPH + c) * HWPIX
                       + (size_t)(wy * 8 + rw) * IMGW + x0 + ch * 8;
        const uint4 v = *reinterpret_cast<const uint4*>(&QKV[g]);
        u16* dst = sMem + tensor * (24 * CS);
        *reinterpret_cast<uint4*>(&dst[c * CS + rw * 40 + ch * 8]) = v;
    }
    __syncthreads();

    if (tid < 192) {
        const int qk = tid / 96;
        const int rem = tid - qk * 96;
        const int ww = rem / 24, c = rem % 24;
        const u16* sT = qk ? sK : sQ;
        const int off = c * CS + ww * 8;
        float s = 0.f;
#pragma unroll
        for (int rw = 0; rw < 8; ++rw) {
            const int rw2 = (rw + c) & 7;
            const short8 v = *reinterpret_cast<const short8*>(&sT[off + rw2 * 40]);
#pragma unroll
            for (int j = 0; j < 8; ++j) {
                const float f = bu2f((u16)v[j]);
                s = fmaf(f, f, s);
            }
        }
        const float inv = 1.f / fmaxf(sqrtf(s), 1e-12f);
        if (qk) snk[ww * 32 + c] = inv; else snq[ww * 32 + c] = inv;
    }
    __syncthreads();

    f32x4 accg[2][2];
#pragma unroll
    for (int i = 0; i < 2; ++i)
#pragma unroll
        for (int j = 0; j < 2; ++j) accg[i][j] = (f32x4){0.f, 0.f, 0.f, 0.f};

    __builtin_amdgcn_s_setprio(1);
#pragma unroll
    for (int kk = 0; kk < 2; ++kk) {
        const int colA = (kk * 4 + hk) * 40 + w * 8;
        const short8 aq0 = *reinterpret_cast<const short8*>(&sQ[(r     ) * CS + colA]);
        const short8 aq1 = *reinterpret_cast<const short8*>(&sQ[(16 + r) * CS + colA]);
        const short8 bk0 = *reinterpret_cast<const short8*>(&sK[(r     ) * CS + colA]);
        const short8 bk1 = *reinterpret_cast<const short8*>(&sK[(16 + r) * CS + colA]);
        accg[0][0] = __builtin_amdgcn_mfma_f32_16x16x32_bf16(aq0, bk0, accg[0][0], 0, 0, 0);
        accg[0][1] = __builtin_amdgcn_mfma_f32_16x16x32_bf16(aq0, bk1, accg[0][1], 0, 0, 0);
        accg[1][0] = __builtin_amdgcn_mfma_f32_16x16x32_bf16(aq1, bk0, accg[1][0], 0, 0, 0);
        accg[1][1] = __builtin_amdgcn_mfma_f32_16x16x32_bf16(aq1, bk1, accg[1][1], 0, 0, 0);
    }
    __builtin_amdgcn_s_setprio(0);
    __syncthreads();   // all Gram reads done before sP (=sQ) writes

    const float t = temp[head];
    const int e0 = lane & 15;
    const bool v1 = e0 < 8;
    const float ink0 = snk[w * 32 + e0];
    const float ink1 = snk[w * 32 + 16 + e0];

#pragma unroll
    for (int ct = 0; ct < 2; ++ct) {
#pragma unroll
        for (int j = 0; j < 4; ++j) {
            const int cidx = ct * 16 + hk * 4 + j;
            const float inq = snq[w * 32 + (cidx < CPH ? cidx : 0)];
            const float g0 = accg[ct][0][j] * inq * ink0 * t;
            const float g1 = v1 ? accg[ct][1][j] * inq * ink1 * t : -1e30f;
            float m = fmaxf(g0, g1);
#pragma unroll
            for (int mk = 8; mk >= 1; mk >>= 1) m = fmaxf(m, __shfl_xor(m, mk));
            const float p0 = __expf(g0 - m);
            const float p1 = v1 ? __expf(g1 - m) : 0.f;
            float s = p0 + p1;
#pragma unroll
            for (int mk = 8; mk >= 1; mk >>= 1) s += __shfl_xor(s, mk);
            const float inv = 1.f / s;
            if (cidx < CPH) {
                sP[w * 32 * PS + cidx * PS + e0] = f2bu(p0 * inv + sAg[cidx * CPH + e0]);
                if (v1) sP[w * 32 * PS + cidx * PS + 16 + e0]
                    = f2bu(p1 * inv + sAg[cidx * CPH + 16 + e0]);
            }
        }
    }
    __syncthreads();

    f32x4 acco[2][4];
#pragma unroll
    for (int i = 0; i < 2; ++i)
#pragma unroll
        for (int j = 0; j < 4; ++j) acco[i][j] = (f32x4){0.f, 0.f, 0.f, 0.f};

    short8 afr[2];
#pragma unroll
    for (int ct = 0; ct < 2; ++ct) {
        if (hk < 3)
            afr[ct] = *reinterpret_cast<const short8*>(
                &sP[w * 32 * PS + (ct * 16 + r) * PS + hk * 8]);
        else
            afr[ct] = (short8){0, 0, 0, 0, 0, 0, 0, 0};
    }
    __builtin_amdgcn_s_setprio(1);
#pragma unroll
    for (int nt = 0; nt < 4; ++nt) {
        const int px = nt * 16 + r;
        const int colV = (px >> 3) * 40 + w * 8 + (px & 7);
        short8 bfr;
        if (hk < 3) {
#pragma unroll
            for (int j = 0; j < 8; ++j)
                bfr[j] = (short)sV[(hk * 8 + j) * CS + colV];
        } else {
            bfr = (short8){0, 0, 0, 0, 0, 0, 0, 0};
        }
        acco[0][nt] = __builtin_amdgcn_mfma_f32_16x16x32_bf16(afr[0], bfr, acco[0][nt], 0, 0, 0);
        acco[1][nt] = __builtin_amdgcn_mfma_f32_16x16x32_bf16(afr[1], bfr, acco[1][nt], 0, 0, 0);
    }
    __builtin_amdgcn_s_setprio(0);

    // ---- epilogue: pixel-major LDS tile sO[local_px 0..255][OS3] then
    // per-thread 48B contiguous global store of its pixel's 24-c slice.
#pragma unroll
    for (int ct = 0; ct < 2; ++ct) {
#pragma unroll
        for (int j = 0; j < 4; ++j) {
            const int cidx = ct * 16 + hk * 4 + j;
            if (cidx >= CPH) continue;
#pragma unroll
            for (int nt = 0; nt < 4; ++nt) {
                const int px = nt * 16 + r;
                const int rpx = px >> 3, pxl = px & 7;
                const int lp = rpx * 32 + w * 8 + pxl;   // 0..255
                sO[lp * OS3 + cidx] = f2bu(acco[ct][nt][j]);
            }
        }
    }
    __syncthreads();

    {
        const int lp = tid;                      // one pixel per thread
        const int gp = (wy * 8 + (lp >> 5)) * IMGW + x0 + (lp & 31);
        const u16* src = &sO[lp * OS3];
        uint2 d0 = *reinterpret_cast<const uint2*>(src);
        uint2 d1 = *reinterpret_cast<const uint2*>(src + 4);
        uint2 d2 = *reinterpret_cast<const uint2*>(src + 8);
        uint2 d3 = *reinterpret_cast<const uint2*>(src + 12);
        uint2 d4 = *reinterpret_cast<const uint2*>(src + 16);
        uint2 d5 = *reinterpret_cast<const uint2*>(src + 20);
        u16* dst = Ot + ((size_t)b * HWPIX + gp) * CDIM + head * CPH;
        uint4 v0 = {d0.x, d0.y, d1.x, d1.y};
        uint4 v1 = {d2.x, d2.y, d3.x, d3.y};
        uint4 v2 = {d4.x, d4.y, d5.x, d5.y};
        *reinterpret_cast<uint4*>(dst)     = v0;
        *reinterpret_cast<uint4*>(dst + 8)  = v1;
        *reinterpret_cast<uint4*>(dst + 16) = v2;
    }
}

// ---------------------------------------------------------------------------
// Global branch stats — MFMA (unchanged).
// ---------------------------------------------------------------------------
#define GRS 520

__global__ __launch_bounds__(256) void gstats_kernel(
    const bf16* __restrict__ QKV, float* __restrict__ Gp)
{
    __shared__ alignas(16) u16 sq[32 * GRS];
    __shared__ alignas(16) u16 sk[32 * GRS];

    const int chunk = blockIdx.x;        // 0..15
    const int bh = blockIdx.y;           // 0..31
    const int b = bh >> 3, head = bh & 7;
    const int tid = threadIdx.x;
    const int w = tid >> 6, lane = tid & 63;
    const int r = lane & 15, hk = lane >> 4;

    const size_t qb = ((size_t)b * C3 + head * CPH) * HWPIX;
    const size_t kb = qb + (size_t)CDIM * HWPIX;

    for (int idx = tid; idx < 1040; idx += 256) {
        const int t = idx >= 520;
        const int o = idx - t * 520;
        u16* d = (t ? sk : sq) + 24 * GRS + o * 8;
        *reinterpret_cast<uint4*>(d) = (uint4){0u, 0u, 0u, 0u};
    }

    f32x4 acc[2][2];
#pragma unroll
    for (int i = 0; i < 2; ++i)
#pragma unroll
        for (int j = 0; j < 2; ++j) acc[i][j] = (f32x4){0.f, 0.f, 0.f, 0.f};
    float nacc = 0.f;
    const int nrow = tid >> 2;
    const int nq4  = tid & 3;

    for (int st = 0; st < 8; ++st) {
        const int d0 = chunk * 4096 + st * 512;
        __syncthreads();
#pragma unroll
        for (int i = 0; i < 12; ++i) {
            const int idx = tid + i * 256;
            const int t = idx >= 1536;
            const int rem = idx - t * 1536;
            const int c = rem >> 6, dv = rem & 63;
            const uint4 v = *reinterpret_cast<const uint4*>(
                &QKV[(t ? kb : qb) + (size_t)c * HWPIX + d0 + dv * 8]);
            u16* dst = (t ? sk : sq) + c * GRS + dv * 8;
            *reinterpret_cast<uint4*>(dst) = v;
        }
        __syncthreads();

#pragma unroll
        for (int ks = 0; ks < 4; ++ks) {
            const int kof = w * 128 + ks * 32 + hk * 8;
            const short8 aq0 = *reinterpret_cast<const short8*>(&sq[(r     ) * GRS + kof]);
            const short8 aq1 = *reinterpret_cast<const short8*>(&sq[(16 + r) * GRS + kof]);
            const short8 bk0 = *reinterpret_cast<const short8*>(&sk[(r     ) * GRS + kof]);
            const short8 bk1 = *reinterpret_cast<const short8*>(&sk[(16 + r) * GRS + kof]);
            acc[0][0] = __builtin_amdgcn_mfma_f32_16x16x32_bf16(aq0, bk0, acc[0][0], 0, 0, 0);
            acc[0][1] = __builtin_amdgcn_mfma_f32_16x16x32_bf16(aq0, bk1, acc[0][1], 0, 0, 0);
            acc[1][0] = __builtin_amdgcn_mfma_f32_16x16x32_bf16(aq1, bk0, acc[1][0], 0, 0, 0);
            acc[1][1] = __builtin_amdgcn_mfma_f32_16x16x32_bf16(aq1, bk1, acc[1][1], 0, 0, 0);
        }

        if (nrow < 48) {
            const u16* rp = (nrow < 24 ? &sq[nrow * GRS] : &sk[(nrow - 24) * GRS]) + nq4 * 128;
#pragma unroll
            for (int i = 0; i < 16; ++i) {
                const short8 v = *reinterpret_cast<const short8*>(&rp[i * 8]);
#pragma unroll
                for (int j = 0; j < 8; ++j) {
                    const float f = bu2f((u16)v[j]);
                    nacc = fmaf(f, f, nacc);
                }
            }
        }
    }
    __syncthreads();

    float* red = reinterpret_cast<float*>(sq);
#pragma unroll
    for (int ct = 0; ct < 2; ++ct) {
#pragma unroll
        for (int et = 0; et < 2; ++et) {
#pragma unroll
            for (int j = 0; j < 4; ++j) {
                const int c = ct * 16 + hk * 4 + j;
                const int e = et * 16 + r;
                if (c < CPH && e < CPH)
                    red[(w * 24 + c) * 25 + e] = acc[ct][et][j];
            }
        }
    }
    __syncthreads();

    float* dst = Gp + ((size_t)bh * 32 + chunk) * 624;
    for (int idx = tid; idx < 576; idx += 256) {
        const int c = idx / 24, e = idx % 24;
        const int o = c * 25 + e;
        dst[idx] = red[o] + red[600 + o] + red[1200 + o] + red[1800 + o];
    }

    float ns = nacc;
    ns += __shfl_xor(ns, 1);
    ns += __shfl_xor(ns, 2);
    if (nrow < 48 && nq4 == 0) {
        if (nrow < 24) dst[576 + nrow] = ns;
        else           dst[600 + (nrow - 24)] = ns;
    }
}

// ---------------------------------------------------------------------------
__global__ __launch_bounds__(64) void gsoftmax_kernel(
    const float* __restrict__ Gp, const float* __restrict__ temp,
    float* __restrict__ A)
{
    __shared__ float red[624];
    const int bh = blockIdx.x, head = bh & 7;
    const int tid = threadIdx.x;

    for (int jj = tid; jj < 624; jj += 64) {
        float s = 0.f;
        for (int ch = 0; ch < 16; ++ch) s += Gp[((size_t)bh * 32 + ch) * 624 + jj];
        red[jj] = s;
    }
    __syncthreads();

    if (tid < CPH) {
        const int c = tid;
        const float t = temp[head];
        const float inq = 1.f / fmaxf(sqrtf(red[576 + c]), 1e-12f);
        float l[CPH]; float m = -1e30f;
        for (int e = 0; e < CPH; ++e) {
            const float ink = 1.f / fmaxf(sqrtf(red[600 + e]), 1e-12f);
            l[e] = red[c * CPH + e] * inq * ink * t;
            m = fmaxf(m, l[e]);
        }
        float s = 0.f;
        for (int e = 0; e < CPH; ++e) { l[e] = expf(l[e] - m); s += l[e]; }
        const float inv = 1.f / s;
        for (int e = 0; e < CPH; ++e) A[(size_t)bh * 576 + c * CPH + e] = l[e] * inv;
    }
}

// ---------------------------------------------------------------------------
extern "C" void kernel_launch(void* const* d_in, const int* in_sizes, int n_in,
                              void* d_out, int out_size, void* d_ws, size_t ws_size,
                              hipStream_t stream) {
    const float* x           = (const float*)d_in[0];
    const float* temperature = (const float*)d_in[1];
    const float* qkv_w       = (const float*)d_in[2];
    const float* qkv_b       = (const float*)d_in[3];
    const float* dw_w        = (const float*)d_in[4];
    const float* dw_b        = (const float*)d_in[5];
    const float* proj_w      = (const float*)d_in[6];
    const float* proj_b      = (const float*)d_in[7];
    float* out = (float*)d_out;

    char* ws = (char*)d_ws;
    constexpr size_t QKV_ELEMS = (size_t)NBATCH * C3 * HWPIX;
    constexpr size_t QKV_BYTES = QKV_ELEMS * sizeof(bf16);

    bf16* qkv1 = (bf16*)ws;                       // conv1x1 out (bf16) [c][p]
    bf16* qkv2 = (bf16*)(ws + QKV_BYTES);         // q,k,v after depthwise
    u16*  osumT = (u16*)ws;                       // o1+o2 bf16 PIXEL-MAJOR [p][192]
    float* Gp   = (float*)(ws + 2 * QKV_BYTES);   // partials
    float* Amat = Gp + (size_t)32 * 32 * 624;
    u16*  Wb    = (u16*)Gp;                       // qkv weights bf16 (dead before gstats)
    u16*  Wpb   = (u16*)(Amat + 32 * 576);        // proj weights bf16
    u16*  Xt    = (u16*)qkv2;                     // Xt overlays qkv2 (dead after conv_qkv)

    // 0. weights f32 -> bf16
    prep_weights<<<(C3 * CDIM + 255) / 256, 256, 0, stream>>>(qkv_w, Wb, C3 * CDIM);
    prep_weights<<<(CDIM * CDIM + 255) / 256, 256, 0, stream>>>(proj_w, Wpb, CDIM * CDIM);

    // 0b. X transpose+convert -> Xt
    xprep_kernel<<<dim3(HWPIX / 64, NBATCH), 256, 0, stream>>>(x, Xt);

    // 1. qkv = 1x1 conv via MFMA (R10 proven structure)
    conv_qkv_mfma<<<9 * 512 * NBATCH, 256, 0, stream>>>(Xt, Wb, qkv_b, qkv1);

    // 2. depthwise 3x3, 32-row tiles (overwrites Xt region — Xt dead)
    dwconv_kernel<<<dim3(8, NBATCH * C3), 256, 0, stream>>>(
        qkv1, dw_w, dw_b, qkv2);

    // 3. global Gram/norm partials via MFMA (overwrites Wb — dead)
    gstats_kernel<<<dim3(16, 32), 256, 0, stream>>>(qkv2, Gp);

    // 4. reduce + softmax -> A
    gsoftmax_kernel<<<32, 64, 0, stream>>>(Gp, temperature, Amat);

    // 5. local attention + fused global apply -> osumT (pixel-major bf16)
    local_attn_kernel<<<dim3(256, NHEADS, NBATCH), 256, 0, stream>>>(
        qkv2, temperature, Amat, osumT);

    // 6. proj 1x1 conv via MFMA (pixel-major bf16 in, f32 out, pure-copy staging)
    conv_proj_mfma<<<3 * 512 * NBATCH, 256, 0, stream>>>(osumT, Wpb, proj_b, out);
}

// Round 14
// 607.675 us; speedup vs baseline: 1.0773x; 1.0773x over previous
//
#include <hip/hip_runtime.h>
#include <hip/hip_bf16.h>
#include <cstdint>
#include <cstddef>

#define HWPIX 65536
#define IMGW 256
#define CDIM 192
#define C3 576
#define NBATCH 4
#define NHEADS 8
#define CPH 24
#define KP 104   // padded K pitch (bf16 elems) for MFMA LDS tiles

using bf16 = __hip_bfloat16;
typedef __attribute__((ext_vector_type(8))) short short8;
typedef __attribute__((ext_vector_type(4))) float f32x4;
typedef unsigned int u32;
typedef unsigned short u16;

__device__ __forceinline__ float b2f(bf16 v) { return __bfloat162float(v); }
__device__ __forceinline__ bf16 f2b(float v) { return __float2bfloat16(v); }
__device__ __forceinline__ float bu2f(u16 h) { return __uint_as_float((u32)h << 16); }
__device__ __forceinline__ u16 f2bu(float x) {
    bf16 h = __float2bfloat16(x);
    return *reinterpret_cast<u16*>(&h);
}
__device__ __forceinline__ u32 pack2(float a, float b) {
    return (u32)f2bu(a) | ((u32)f2bu(b) << 16);
}

// ---------------------------------------------------------------------------
// Convert weights f32 -> bf16 (u16).
// ---------------------------------------------------------------------------
__global__ __launch_bounds__(256) void prep_weights(
    const float* __restrict__ W, u16* __restrict__ Wb, int n)
{
    int i = blockIdx.x * 256 + threadIdx.x;
    if (i < n) Wb[i] = f2bu(W[i]);
}

// ---------------------------------------------------------------------------
// X f32 [b][k][p] -> Xt bf16 [b][p][k]  (one-time transpose+convert).
// ---------------------------------------------------------------------------
__global__ __launch_bounds__(256) void xprep_kernel(
    const float* __restrict__ X, u16* __restrict__ Xt)
{
    __shared__ float sX[CDIM * 68];
    const int b  = blockIdx.y;
    const int p0 = blockIdx.x * 64;
    const int tid = threadIdx.x;

#pragma unroll
    for (int i = 0; i < 12; ++i) {
        const int idx = tid + i * 256;        // 0..3071 float4s
        const int p4 = idx & 15, k = idx >> 4;
        const float4 v = *reinterpret_cast<const float4*>(
            X + ((size_t)b * CDIM + k) * HWPIX + p0 + p4 * 4);
        *reinterpret_cast<float4*>(&sX[k * 68 + p4 * 4]) = v;
    }
    __syncthreads();

    const int p = tid >> 2;          // 0..63
    const int seg = tid & 3;         // 0..3 (6 k-blocks each)
    u16* dst = Xt + ((size_t)b * HWPIX + p0 + p) * CDIM;
#pragma unroll
    for (int s = 0; s < 6; ++s) {
        const int blk = seg * 6 + s; // 0..23, 8 k each
        float f[8];
#pragma unroll
        for (int j = 0; j < 8; ++j) f[j] = sX[(blk * 8 + j) * 68 + p];
        uint4 ov;
        ov.x = pack2(f[0], f[1]);
        ov.y = pack2(f[2], f[3]);
        ov.z = pack2(f[4], f[5]);
        ov.w = pack2(f[6], f[7]);
        *reinterpret_cast<uint4*>(dst + blk * 8) = ov;
    }
}

// ---------------------------------------------------------------------------
// Shared MFMA inner block (R10 proven structure).
// ---------------------------------------------------------------------------
__device__ __forceinline__ void chunk_mfma(
    const u16* sA, const u16* sB, int r, int hk, int wave, f32x4 (&acc)[4][2])
{
#pragma unroll
    for (int ks = 0; ks < 3; ++ks) {
        const int kof = ks * 32 + hk * 8;
        const u16* pA = &sA[r * KP + kof];
        const u16* pB = &sB[(wave * 32 + r) * KP + kof];
        const short8 a0 = *reinterpret_cast<const short8*>(pA);
        const short8 a1 = *reinterpret_cast<const short8*>(pA + 16 * KP);
        const short8 a2 = *reinterpret_cast<const short8*>(pA + 32 * KP);
        const short8 a3 = *reinterpret_cast<const short8*>(pA + 48 * KP);
        const short8 b0 = *reinterpret_cast<const short8*>(pB);
        const short8 b1 = *reinterpret_cast<const short8*>(pB + 16 * KP);
        acc[0][0] = __builtin_amdgcn_mfma_f32_16x16x32_bf16(a0, b0, acc[0][0], 0, 0, 0);
        acc[1][0] = __builtin_amdgcn_mfma_f32_16x16x32_bf16(a1, b0, acc[1][0], 0, 0, 0);
        acc[2][0] = __builtin_amdgcn_mfma_f32_16x16x32_bf16(a2, b0, acc[2][0], 0, 0, 0);
        acc[3][0] = __builtin_amdgcn_mfma_f32_16x16x32_bf16(a3, b0, acc[3][0], 0, 0, 0);
        acc[0][1] = __builtin_amdgcn_mfma_f32_16x16x32_bf16(a0, b1, acc[0][1], 0, 0, 0);
        acc[1][1] = __builtin_amdgcn_mfma_f32_16x16x32_bf16(a1, b1, acc[1][1], 0, 0, 0);
        acc[2][1] = __builtin_amdgcn_mfma_f32_16x16x32_bf16(a2, b1, acc[2][1], 0, 0, 0);
        acc[3][1] = __builtin_amdgcn_mfma_f32_16x16x32_bf16(a3, b1, acc[3][1], 0, 0, 0);
    }
}

// ---------------------------------------------------------------------------
// qkv 1x1 conv (exact R10 structure): Y bf16 [b][co][p].
// ---------------------------------------------------------------------------
__global__ __launch_bounds__(256, 4) void conv_qkv_mfma(
    const u16* __restrict__ Xt, const u16* __restrict__ Wb,
    const float* __restrict__ bias, bf16* __restrict__ Y)
{
    __shared__ alignas(16) u16 sA[64 * KP];
    __shared__ alignas(16) u16 sB[128 * KP];
    __shared__ float sBias[64];

    int lin = blockIdx.x;
    lin = (lin & 7) * (18432 / 8) + (lin >> 3);
    const int co_t = lin % 9;
    const int rest = lin / 9;
    const int p_t = rest & 511;
    const int b   = rest >> 9;
    const int co0 = co_t * 64;
    const int p0  = p_t * 128;

    const int tid  = threadIdx.x;
    const int wave = tid >> 6;
    const int lane = tid & 63;
    const int r  = lane & 15;
    const int hk = lane >> 4;

    if (tid < 64) sBias[tid] = bias[co0 + tid];

    f32x4 acc[4][2];
#pragma unroll
    for (int i = 0; i < 4; ++i)
#pragma unroll
        for (int j = 0; j < 2; ++j) acc[i][j] = (f32x4){0.f, 0.f, 0.f, 0.f};

#pragma unroll
    for (int c = 0; c < 2; ++c) {
        {
            int idx = tid;
#pragma unroll
            for (int i = 0; i < 3; ++i, idx += 256) {
                const int row = idx / 12, cv = idx % 12;
                const uint4 v = *reinterpret_cast<const uint4*>(
                    Wb + (size_t)(co0 + row) * CDIM + c * 96 + cv * 8);
                *reinterpret_cast<uint4*>(&sA[row * KP + cv * 8]) = v;
            }
        }
        {
            int idx = tid;
#pragma unroll
            for (int i = 0; i < 6; ++i, idx += 256) {
                const int row = idx / 12, cv = idx % 12;
                const uint4 v = *reinterpret_cast<const uint4*>(
                    Xt + ((size_t)b * HWPIX + p0 + row) * CDIM + c * 96 + cv * 8);
                *reinterpret_cast<uint4*>(&sB[row * KP + cv * 8]) = v;
            }
        }
        __syncthreads();
        chunk_mfma(sA, sB, r, hk, wave, acc);
        __syncthreads();
    }

#define OS2 132
    u16* sOut = sB;
#pragma unroll
    for (int mf = 0; mf < 4; ++mf) {
#pragma unroll
        for (int j = 0; j < 4; ++j) {
            const int row = mf * 16 + hk * 4 + j;
            const float bs = sBias[row];
            sOut[row * OS2 + wave * 32 + r]      = f2bu(acc[mf][0][j] + bs);
            sOut[row * OS2 + wave * 32 + r + 16] = f2bu(acc[mf][1][j] + bs);
        }
    }
    __syncthreads();
#pragma unroll
    for (int i = 0; i < 4; ++i) {
        const int idx = tid + i * 256;
        const int row = idx >> 4, cq = idx & 15;
        const u16* src = &sOut[row * OS2 + cq * 8];
        const uint2 lo = *reinterpret_cast<const uint2*>(src);
        const uint2 hi = *reinterpret_cast<const uint2*>(src + 4);
        uint4 v = {lo.x, lo.y, hi.x, hi.y};
        *reinterpret_cast<uint4*>(
            &Y[((size_t)b * C3 + co0 + row) * HWPIX + p0 + cq * 8]) = v;
    }
}

// ---------------------------------------------------------------------------
// proj 1x1 conv — reads head-grouped pixel-major osum Ot [b][head][p][24]
// bf16. Staging is pure uint4 copy: chunk c covers heads 4c..4c+3; each
// (row,h) contributes 3 aligned uint4 (p*24 u16 = 48B, 16B-aligned).
// k-order in sB = global channel order (head*24+c) = W's k order.
// ---------------------------------------------------------------------------
__global__ __launch_bounds__(256, 4) void conv_proj_mfma(
    const u16* __restrict__ Ot, const u16* __restrict__ Wb,
    const float* __restrict__ bias, float* __restrict__ Y)
{
    __shared__ alignas(16) u16 sA[64 * KP];
    __shared__ alignas(16) u16 sB[128 * KP];
    __shared__ float sBias[64];

    int lin = blockIdx.x;                       // nwg = 6144
    lin = (lin & 7) * (6144 / 8) + (lin >> 3);
    const int co_t = lin % 3;
    const int rest = lin / 3;
    const int p_t = rest & 511;
    const int b   = rest >> 9;
    const int co0 = co_t * 64;
    const int p0  = p_t * 128;

    const int tid  = threadIdx.x;
    const int wave = tid >> 6;
    const int lane = tid & 63;
    const int r  = lane & 15;
    const int hk = lane >> 4;

    if (tid < 64) sBias[tid] = bias[co0 + tid];

    f32x4 acc[4][2];
#pragma unroll
    for (int i = 0; i < 4; ++i)
#pragma unroll
        for (int j = 0; j < 2; ++j) acc[i][j] = (f32x4){0.f, 0.f, 0.f, 0.f};

#pragma unroll
    for (int c = 0; c < 2; ++c) {
        {
            int idx = tid;
#pragma unroll
            for (int i = 0; i < 3; ++i, idx += 256) {
                const int row = idx / 12, cv = idx % 12;
                const uint4 v = *reinterpret_cast<const uint4*>(
                    Wb + (size_t)(co0 + row) * CDIM + c * 96 + cv * 8);
                *reinterpret_cast<uint4*>(&sA[row * KP + cv * 8]) = v;
            }
        }
        {
            // B: 128 rows x 4 heads x 3 uint4 = 1536 uint4, 6/thread
            int idx = tid;
#pragma unroll
            for (int i = 0; i < 6; ++i, idx += 256) {
                const int row = idx / 12, sub = idx % 12;
                const int h = c * 4 + sub / 3, part = sub % 3;
                const uint4 v = *reinterpret_cast<const uint4*>(
                    Ot + ((size_t)(b * NHEADS + h) * HWPIX + p0 + row) * CPH + part * 8);
                *reinterpret_cast<uint4*>(
                    &sB[row * KP + (sub / 3) * 24 + part * 8]) = v;
            }
        }
        __syncthreads();
        chunk_mfma(sA, sB, r, hk, wave, acc);
        __syncthreads();
    }

    // epilogue: f32 stores, 16-lane groups are 64B contiguous
#pragma unroll
    for (int mf = 0; mf < 4; ++mf) {
#pragma unroll
        for (int j = 0; j < 4; ++j) {
            const int co = co0 + mf * 16 + hk * 4 + j;
            const float bs = sBias[mf * 16 + hk * 4 + j];
            const size_t base = ((size_t)b * CDIM + co) * HWPIX + p0 + wave * 32 + r;
            Y[base]      = acc[mf][0][j] + bs;
            Y[base + 16] = acc[mf][1][j] + bs;
        }
    }
}

// ---------------------------------------------------------------------------
// Depthwise 3x3 SAME conv — 32-row tiles (unchanged).
// ---------------------------------------------------------------------------
__global__ __launch_bounds__(256) void dwconv_kernel(
    const bf16* __restrict__ In, const float* __restrict__ Wd,
    const float* __restrict__ bd, bf16* __restrict__ Out)
{
    __shared__ alignas(16) u16 sIn[34 * 256];   // 17408 B
    const int bc = blockIdx.y;            // b*576 + c
    const int c = bc % C3;
    const size_t base = (size_t)bc * HWPIX;
    const int r0 = blockIdx.x * 32;
    const int tid = threadIdx.x;

    for (int idx = tid; idx < 34 * 32; idx += 256) {
        const int lr = idx >> 5, ch = idx & 31;
        const int gr = r0 + lr - 1;
        uint4 v = {0u, 0u, 0u, 0u};
        if ((unsigned)gr < IMGW)
            v = *reinterpret_cast<const uint4*>(&In[base + (size_t)gr * IMGW + ch * 8]);
        *reinterpret_cast<uint4*>(&sIn[lr * 256 + ch * 8]) = v;
    }
    __syncthreads();

    float wg[9];
#pragma unroll
    for (int t = 0; t < 9; ++t) wg[t] = Wd[c * 9 + t];

    const int rr  = tid >> 5;             // 0..7
    const int px0 = (tid & 31) * 8;
    const float bias = bd[c];

#pragma unroll
    for (int kk = 0; kk < 4; ++kk) {
        const int orow = rr + kk * 8;     // output row within tile 0..31
        float acc[8];
#pragma unroll
        for (int j = 0; j < 8; ++j) acc[j] = bias;

#pragma unroll
        for (int dy = 0; dy < 3; ++dy) {
            const u16* rp = &sIn[(orow + dy) * 256];
            const short8 mv = *reinterpret_cast<const short8*>(&rp[px0]);
            float m[8];
#pragma unroll
            for (int j = 0; j < 8; ++j) m[j] = bu2f((u16)mv[j]);
            const float lft = (px0 > 0) ? bu2f(rp[px0 - 1]) : 0.f;
            const float rgt = (px0 + 8 < 256) ? bu2f(rp[px0 + 8]) : 0.f;
            const float w0 = wg[dy * 3], w1 = wg[dy * 3 + 1], w2 = wg[dy * 3 + 2];

            acc[0] = fmaf(w0, lft, acc[0]);
            acc[0] = fmaf(w1, m[0], acc[0]);
            acc[0] = fmaf(w2, m[1], acc[0]);
#pragma unroll
            for (int j = 1; j < 7; ++j) {
                acc[j] = fmaf(w0, m[j - 1], acc[j]);
                acc[j] = fmaf(w1, m[j], acc[j]);
                acc[j] = fmaf(w2, m[j + 1], acc[j]);
            }
            acc[7] = fmaf(w0, m[6], acc[7]);
            acc[7] = fmaf(w1, m[7], acc[7]);
            acc[7] = fmaf(w2, rgt, acc[7]);
        }

        uint4 ov;
        ov.x = pack2(acc[0], acc[1]);
        ov.y = pack2(acc[2], acc[3]);
        ov.z = pack2(acc[4], acc[5]);
        ov.w = pack2(acc[6], acc[7]);
        *reinterpret_cast<uint4*>(&Out[base + (size_t)(r0 + orow) * IMGW + px0]) = ov;
    }
}

// ---------------------------------------------------------------------------
// Local (windowed 8x8) channel attention + fused global apply.
// R14: epilogue writes Ot [b][head][p][24] bf16 — per block the 32 px of a
// row form a 1536B contiguous span (full 64B lines, no cross-block sharing).
// ---------------------------------------------------------------------------
#define CS 328          // c-row stride (u16)
#define PS 40           // row stride (u16) for sP
#define OS3 28          // pixel-major out tile stride (u16)

__global__ __launch_bounds__(256, 3) void local_attn_kernel(
    const bf16* __restrict__ QKV, const float* __restrict__ temp,
    const float* __restrict__ Ag, u16* __restrict__ Ot)
{
    __shared__ alignas(16) u16 sMem[3 * 24 * CS];
    __shared__ float snq[4 * 32], snk[4 * 32];
    __shared__ float sAg[576];
    u16* const sQ = sMem;
    u16* const sK = sMem + 24 * CS;
    u16* const sV = sMem + 48 * CS;
    u16* const sP = sQ;     // overlay: sQ dead after Gram (barrier-protected)
    u16* const sO = sK;     // overlay: sK dead after Gram (256*28=7168 <= 7872)

    const int wy    = blockIdx.x >> 3;
    const int strip = blockIdx.x & 7;
    const int head  = blockIdx.y;
    const int b     = blockIdx.z;
    const int x0    = strip * 32;
    const int tid   = threadIdx.x;
    const int w     = tid >> 6;
    const int lane  = tid & 63;
    const int r     = lane & 15;
    const int hk    = lane >> 4;

    {
        const float* Asrc = Ag + ((size_t)(b * NHEADS + head)) * 576;
        for (int idx = tid; idx < 576; idx += 256) sAg[idx] = Asrc[idx];
    }

#pragma unroll
    for (int i = 0; i < 9; ++i) {
        const int idx = tid + i * 256;
        const int tensor = idx / 768;
        const int rem = idx - tensor * 768;
        const int c  = rem >> 5;
        const int rw = (rem >> 2) & 7;
        const int ch = rem & 3;
        const size_t g = ((size_t)b * C3 + tensor * CDIM + head * CPH + c) * HWPIX
                       + (size_t)(wy * 8 + rw) * IMGW + x0 + ch * 8;
        const uint4 v = *reinterpret_cast<const uint4*>(&QKV[g]);
        u16* dst = sMem + tensor * (24 * CS);
        *reinterpret_cast<uint4*>(&dst[c * CS + rw * 40 + ch * 8]) = v;
    }
    __syncthreads();

    if (tid < 192) {
        const int qk = tid / 96;
        const int rem = tid - qk * 96;
        const int ww = rem / 24, c = rem % 24;
        const u16* sT = qk ? sK : sQ;
        const int off = c * CS + ww * 8;
        float s = 0.f;
#pragma unroll
        for (int rw = 0; rw < 8; ++rw) {
            const int rw2 = (rw + c) & 7;
            const short8 v = *reinterpret_cast<const short8*>(&sT[off + rw2 * 40]);
#pragma unroll
            for (int j = 0; j < 8; ++j) {
                const float f = bu2f((u16)v[j]);
                s = fmaf(f, f, s);
            }
        }
        const float inv = 1.f / fmaxf(sqrtf(s), 1e-12f);
        if (qk) snk[ww * 32 + c] = inv; else snq[ww * 32 + c] = inv;
    }
    __syncthreads();

    f32x4 accg[2][2];
#pragma unroll
    for (int i = 0; i < 2; ++i)
#pragma unroll
        for (int j = 0; j < 2; ++j) accg[i][j] = (f32x4){0.f, 0.f, 0.f, 0.f};

    __builtin_amdgcn_s_setprio(1);
#pragma unroll
    for (int kk = 0; kk < 2; ++kk) {
        const int colA = (kk * 4 + hk) * 40 + w * 8;
        const short8 aq0 = *reinterpret_cast<const short8*>(&sQ[(r     ) * CS + colA]);
        const short8 aq1 = *reinterpret_cast<const short8*>(&sQ[(16 + r) * CS + colA]);
        const short8 bk0 = *reinterpret_cast<const short8*>(&sK[(r     ) * CS + colA]);
        const short8 bk1 = *reinterpret_cast<const short8*>(&sK[(16 + r) * CS + colA]);
        accg[0][0] = __builtin_amdgcn_mfma_f32_16x16x32_bf16(aq0, bk0, accg[0][0], 0, 0, 0);
        accg[0][1] = __builtin_amdgcn_mfma_f32_16x16x32_bf16(aq0, bk1, accg[0][1], 0, 0, 0);
        accg[1][0] = __builtin_amdgcn_mfma_f32_16x16x32_bf16(aq1, bk0, accg[1][0], 0, 0, 0);
        accg[1][1] = __builtin_amdgcn_mfma_f32_16x16x32_bf16(aq1, bk1, accg[1][1], 0, 0, 0);
    }
    __builtin_amdgcn_s_setprio(0);
    __syncthreads();   // all Gram reads done before sP (=sQ) writes

    const float t = temp[head];
    const int e0 = lane & 15;
    const bool v1 = e0 < 8;
    const float ink0 = snk[w * 32 + e0];
    const float ink1 = snk[w * 32 + 16 + e0];

#pragma unroll
    for (int ct = 0; ct < 2; ++ct) {
#pragma unroll
        for (int j = 0; j < 4; ++j) {
            const int cidx = ct * 16 + hk * 4 + j;
            const float inq = snq[w * 32 + (cidx < CPH ? cidx : 0)];
            const float g0 = accg[ct][0][j] * inq * ink0 * t;
            const float g1 = v1 ? accg[ct][1][j] * inq * ink1 * t : -1e30f;
            float m = fmaxf(g0, g1);
#pragma unroll
            for (int mk = 8; mk >= 1; mk >>= 1) m = fmaxf(m, __shfl_xor(m, mk));
            const float p0 = __expf(g0 - m);
            const float p1 = v1 ? __expf(g1 - m) : 0.f;
            float s = p0 + p1;
#pragma unroll
            for (int mk = 8; mk >= 1; mk >>= 1) s += __shfl_xor(s, mk);
            const float inv = 1.f / s;
            if (cidx < CPH) {
                sP[w * 32 * PS + cidx * PS + e0] = f2bu(p0 * inv + sAg[cidx * CPH + e0]);
                if (v1) sP[w * 32 * PS + cidx * PS + 16 + e0]
                    = f2bu(p1 * inv + sAg[cidx * CPH + 16 + e0]);
            }
        }
    }
    __syncthreads();

    f32x4 acco[2][4];
#pragma unroll
    for (int i = 0; i < 2; ++i)
#pragma unroll
        for (int j = 0; j < 4; ++j) acco[i][j] = (f32x4){0.f, 0.f, 0.f, 0.f};

    short8 afr[2];
#pragma unroll
    for (int ct = 0; ct < 2; ++ct) {
        if (hk < 3)
            afr[ct] = *reinterpret_cast<const short8*>(
                &sP[w * 32 * PS + (ct * 16 + r) * PS + hk * 8]);
        else
            afr[ct] = (short8){0, 0, 0, 0, 0, 0, 0, 0};
    }
    __builtin_amdgcn_s_setprio(1);
#pragma unroll
    for (int nt = 0; nt < 4; ++nt) {
        const int px = nt * 16 + r;
        const int colV = (px >> 3) * 40 + w * 8 + (px & 7);
        short8 bfr;
        if (hk < 3) {
#pragma unroll
            for (int j = 0; j < 8; ++j)
                bfr[j] = (short)sV[(hk * 8 + j) * CS + colV];
        } else {
            bfr = (short8){0, 0, 0, 0, 0, 0, 0, 0};
        }
        acco[0][nt] = __builtin_amdgcn_mfma_f32_16x16x32_bf16(afr[0], bfr, acco[0][nt], 0, 0, 0);
        acco[1][nt] = __builtin_amdgcn_mfma_f32_16x16x32_bf16(afr[1], bfr, acco[1][nt], 0, 0, 0);
    }
    __builtin_amdgcn_s_setprio(0);

    // ---- epilogue: pixel-major LDS tile sO[local_px][OS3], then per-thread
    // 48B contiguous store into Ot[b][head][p][24] (full-line coalesced:
    // 32 px/row x 48B = 1536B contiguous span per block-row).
#pragma unroll
    for (int ct = 0; ct < 2; ++ct) {
#pragma unroll
        for (int j = 0; j < 4; ++j) {
            const int cidx = ct * 16 + hk * 4 + j;
            if (cidx >= CPH) continue;
#pragma unroll
            for (int nt = 0; nt < 4; ++nt) {
                const int px = nt * 16 + r;
                const int rpx = px >> 3, pxl = px & 7;
                const int lp = rpx * 32 + w * 8 + pxl;   // 0..255
                sO[lp * OS3 + cidx] = f2bu(acco[ct][nt][j]);
            }
        }
    }
    __syncthreads();

    {
        const int lp = tid;                      // one pixel per thread
        const int gp = (wy * 8 + (lp >> 5)) * IMGW + x0 + (lp & 31);
        const u16* src = &sO[lp * OS3];
        uint2 d0 = *reinterpret_cast<const uint2*>(src);
        uint2 d1 = *reinterpret_cast<const uint2*>(src + 4);
        uint2 d2 = *reinterpret_cast<const uint2*>(src + 8);
        uint2 d3 = *reinterpret_cast<const uint2*>(src + 12);
        uint2 d4 = *reinterpret_cast<const uint2*>(src + 16);
        uint2 d5 = *reinterpret_cast<const uint2*>(src + 20);
        u16* dst = Ot + ((size_t)(b * NHEADS + head) * HWPIX + gp) * CPH;
        uint4 v0 = {d0.x, d0.y, d1.x, d1.y};
        uint4 v1 = {d2.x, d2.y, d3.x, d3.y};
        uint4 v2 = {d4.x, d4.y, d5.x, d5.y};
        *reinterpret_cast<uint4*>(dst)      = v0;
        *reinterpret_cast<uint4*>(dst + 8)  = v1;
        *reinterpret_cast<uint4*>(dst + 16) = v2;
    }
}

// ---------------------------------------------------------------------------
// Global branch stats — MFMA (unchanged).
// ---------------------------------------------------------------------------
#define GRS 520

__global__ __launch_bounds__(256) void gstats_kernel(
    const bf16* __restrict__ QKV, float* __restrict__ Gp)
{
    __shared__ alignas(16) u16 sq[32 * GRS];
    __shared__ alignas(16) u16 sk[32 * GRS];

    const int chunk = blockIdx.x;        // 0..15
    const int bh = blockIdx.y;           // 0..31
    const int b = bh >> 3, head = bh & 7;
    const int tid = threadIdx.x;
    const int w = tid >> 6, lane = tid & 63;
    const int r = lane & 15, hk = lane >> 4;

    const size_t qb = ((size_t)b * C3 + head * CPH) * HWPIX;
    const size_t kb = qb + (size_t)CDIM * HWPIX;

    for (int idx = tid; idx < 1040; idx += 256) {
        const int t = idx >= 520;
        const int o = idx - t * 520;
        u16* d = (t ? sk : sq) + 24 * GRS + o * 8;
        *reinterpret_cast<uint4*>(d) = (uint4){0u, 0u, 0u, 0u};
    }

    f32x4 acc[2][2];
#pragma unroll
    for (int i = 0; i < 2; ++i)
#pragma unroll
        for (int j = 0; j < 2; ++j) acc[i][j] = (f32x4){0.f, 0.f, 0.f, 0.f};
    float nacc = 0.f;
    const int nrow = tid >> 2;
    const int nq4  = tid & 3;

    for (int st = 0; st < 8; ++st) {
        const int d0 = chunk * 4096 + st * 512;
        __syncthreads();
#pragma unroll
        for (int i = 0; i < 12; ++i) {
            const int idx = tid + i * 256;
            const int t = idx >= 1536;
            const int rem = idx - t * 1536;
            const int c = rem >> 6, dv = rem & 63;
            const uint4 v = *reinterpret_cast<const uint4*>(
                &QKV[(t ? kb : qb) + (size_t)c * HWPIX + d0 + dv * 8]);
            u16* dst = (t ? sk : sq) + c * GRS + dv * 8;
            *reinterpret_cast<uint4*>(dst) = v;
        }
        __syncthreads();

#pragma unroll
        for (int ks = 0; ks < 4; ++ks) {
            const int kof = w * 128 + ks * 32 + hk * 8;
            const short8 aq0 = *reinterpret_cast<const short8*>(&sq[(r     ) * GRS + kof]);
            const short8 aq1 = *reinterpret_cast<const short8*>(&sq[(16 + r) * GRS + kof]);
            const short8 bk0 = *reinterpret_cast<const short8*>(&sk[(r     ) * GRS + kof]);
            const short8 bk1 = *reinterpret_cast<const short8*>(&sk[(16 + r) * GRS + kof]);
            acc[0][0] = __builtin_amdgcn_mfma_f32_16x16x32_bf16(aq0, bk0, acc[0][0], 0, 0, 0);
            acc[0][1] = __builtin_amdgcn_mfma_f32_16x16x32_bf16(aq0, bk1, acc[0][1], 0, 0, 0);
            acc[1][0] = __builtin_amdgcn_mfma_f32_16x16x32_bf16(aq1, bk0, acc[1][0], 0, 0, 0);
            acc[1][1] = __builtin_amdgcn_mfma_f32_16x16x32_bf16(aq1, bk1, acc[1][1], 0, 0, 0);
        }

        if (nrow < 48) {
            const u16* rp = (nrow < 24 ? &sq[nrow * GRS] : &sk[(nrow - 24) * GRS]) + nq4 * 128;
#pragma unroll
            for (int i = 0; i < 16; ++i) {
                const short8 v = *reinterpret_cast<const short8*>(&rp[i * 8]);
#pragma unroll
                for (int j = 0; j < 8; ++j) {
                    const float f = bu2f((u16)v[j]);
                    nacc = fmaf(f, f, nacc);
                }
            }
        }
    }
    __syncthreads();

    float* red = reinterpret_cast<float*>(sq);
#pragma unroll
    for (int ct = 0; ct < 2; ++ct) {
#pragma unroll
        for (int et = 0; et < 2; ++et) {
#pragma unroll
            for (int j = 0; j < 4; ++j) {
                const int c = ct * 16 + hk * 4 + j;
                const int e = et * 16 + r;
                if (c < CPH && e < CPH)
                    red[(w * 24 + c) * 25 + e] = acc[ct][et][j];
            }
        }
    }
    __syncthreads();

    float* dst = Gp + ((size_t)bh * 32 + chunk) * 624;
    for (int idx = tid; idx < 576; idx += 256) {
        const int c = idx / 24, e = idx % 24;
        const int o = c * 25 + e;
        dst[idx] = red[o] + red[600 + o] + red[1200 + o] + red[1800 + o];
    }

    float ns = nacc;
    ns += __shfl_xor(ns, 1);
    ns += __shfl_xor(ns, 2);
    if (nrow < 48 && nq4 == 0) {
        if (nrow < 24) dst[576 + nrow] = ns;
        else           dst[600 + (nrow - 24)] = ns;
    }
}

// ---------------------------------------------------------------------------
__global__ __launch_bounds__(64) void gsoftmax_kernel(
    const float* __restrict__ Gp, const float* __restrict__ temp,
    float* __restrict__ A)
{
    __shared__ float red[624];
    const int bh = blockIdx.x, head = bh & 7;
    const int tid = threadIdx.x;

    for (int jj = tid; jj < 624; jj += 64) {
        float s = 0.f;
        for (int ch = 0; ch < 16; ++ch) s += Gp[((size_t)bh * 32 + ch) * 624 + jj];
        red[jj] = s;
    }
    __syncthreads();

    if (tid < CPH) {
        const int c = tid;
        const float t = temp[head];
        const float inq = 1.f / fmaxf(sqrtf(red[576 + c]), 1e-12f);
        float l[CPH]; float m = -1e30f;
        for (int e = 0; e < CPH; ++e) {
            const float ink = 1.f / fmaxf(sqrtf(red[600 + e]), 1e-12f);
            l[e] = red[c * CPH + e] * inq * ink * t;
            m = fmaxf(m, l[e]);
        }
        float s = 0.f;
        for (int e = 0; e < CPH; ++e) { l[e] = expf(l[e] - m); s += l[e]; }
        const float inv = 1.f / s;
        for (int e = 0; e < CPH; ++e) A[(size_t)bh * 576 + c * CPH + e] = l[e] * inv;
    }
}

// ---------------------------------------------------------------------------
extern "C" void kernel_launch(void* const* d_in, const int* in_sizes, int n_in,
                              void* d_out, int out_size, void* d_ws, size_t ws_size,
                              hipStream_t stream) {
    const float* x           = (const float*)d_in[0];
    const float* temperature = (const float*)d_in[1];
    const float* qkv_w       = (const float*)d_in[2];
    const float* qkv_b       = (const float*)d_in[3];
    const float* dw_w        = (const float*)d_in[4];
    const float* dw_b        = (const float*)d_in[5];
    const float* proj_w      = (const float*)d_in[6];
    const float* proj_b      = (const float*)d_in[7];
    float* out = (float*)d_out;

    char* ws = (char*)d_ws;
    constexpr size_t QKV_ELEMS = (size_t)NBATCH * C3 * HWPIX;
    constexpr size_t QKV_BYTES = QKV_ELEMS * sizeof(bf16);

    bf16* qkv1 = (bf16*)ws;                       // conv1x1 out (bf16) [c][p]
    bf16* qkv2 = (bf16*)(ws + QKV_BYTES);         // q,k,v after depthwise
    u16*  osumT = (u16*)ws;                       // o1+o2 bf16 [b][head][p][24]
    float* Gp   = (float*)(ws + 2 * QKV_BYTES);   // partials
    float* Amat = Gp + (size_t)32 * 32 * 624;
    u16*  Wb    = (u16*)Gp;                       // qkv weights bf16 (dead before gstats)
    u16*  Wpb   = (u16*)(Amat + 32 * 576);        // proj weights bf16
    u16*  Xt    = (u16*)qkv2;                     // Xt overlays qkv2 (dead after conv_qkv)

    // 0. weights f32 -> bf16
    prep_weights<<<(C3 * CDIM + 255) / 256, 256, 0, stream>>>(qkv_w, Wb, C3 * CDIM);
    prep_weights<<<(CDIM * CDIM + 255) / 256, 256, 0, stream>>>(proj_w, Wpb, CDIM * CDIM);

    // 0b. X transpose+convert -> Xt
    xprep_kernel<<<dim3(HWPIX / 64, NBATCH), 256, 0, stream>>>(x, Xt);

    // 1. qkv = 1x1 conv via MFMA (R10 proven structure)
    conv_qkv_mfma<<<9 * 512 * NBATCH, 256, 0, stream>>>(Xt, Wb, qkv_b, qkv1);

    // 2. depthwise 3x3, 32-row tiles (overwrites Xt region — Xt dead)
    dwconv_kernel<<<dim3(8, NBATCH * C3), 256, 0, stream>>>(
        qkv1, dw_w, dw_b, qkv2);

    // 3. global Gram/norm partials via MFMA (overwrites Wb — dead)
    gstats_kernel<<<dim3(16, 32), 256, 0, stream>>>(qkv2, Gp);

    // 4. reduce + softmax -> A
    gsoftmax_kernel<<<32, 64, 0, stream>>>(Gp, temperature, Amat);

    // 5. local attention + fused global apply -> osumT [b][head][p][24]
    local_attn_kernel<<<dim3(256, NHEADS, NBATCH), 256, 0, stream>>>(
        qkv2, temperature, Amat, osumT);

    // 6. proj 1x1 conv via MFMA (head-grouped bf16 in, f32 out, pure-copy staging)
    conv_proj_mfma<<<3 * 512 * NBATCH, 256, 0, stream>>>(osumT, Wpb, proj_b, out);
}

// Round 15
// 593.218 us; speedup vs baseline: 1.1036x; 1.0244x over previous
//
#include <hip/hip_runtime.h>
#include <hip/hip_bf16.h>
#include <cstdint>
#include <cstddef>

#define HWPIX 65536
#define IMGW 256
#define CDIM 192
#define C3 576
#define NBATCH 4
#define NHEADS 8
#define CPH 24
#define KP 104   // padded K pitch (bf16 elems) for MFMA LDS tiles

using bf16 = __hip_bfloat16;
typedef __attribute__((ext_vector_type(8))) short short8;
typedef __attribute__((ext_vector_type(4))) float f32x4;
typedef unsigned int u32;
typedef unsigned short u16;

__device__ __forceinline__ float b2f(bf16 v) { return __bfloat162float(v); }
__device__ __forceinline__ bf16 f2b(float v) { return __float2bfloat16(v); }
__device__ __forceinline__ float bu2f(u16 h) { return __uint_as_float((u32)h << 16); }
__device__ __forceinline__ u16 f2bu(float x) {
    bf16 h = __float2bfloat16(x);
    return *reinterpret_cast<u16*>(&h);
}
__device__ __forceinline__ u32 pack2(float a, float b) {
    return (u32)f2bu(a) | ((u32)f2bu(b) << 16);
}

// ---------------------------------------------------------------------------
// Convert BOTH weight tensors f32 -> bf16 in one launch.
// ---------------------------------------------------------------------------
__global__ __launch_bounds__(256) void prep_weights2(
    const float* __restrict__ W1, u16* __restrict__ O1, int n1,
    const float* __restrict__ W2, u16* __restrict__ O2, int n2)
{
    int i = blockIdx.x * 256 + threadIdx.x;
    if (i < n1) O1[i] = f2bu(W1[i]);
    else if (i < n1 + n2) O2[i - n1] = f2bu(W2[i - n1]);
}

// ---------------------------------------------------------------------------
// X f32 [b][k][p] -> Xt bf16 [b][p][k]  (one-time transpose+convert).
// ---------------------------------------------------------------------------
__global__ __launch_bounds__(256) void xprep_kernel(
    const float* __restrict__ X, u16* __restrict__ Xt)
{
    __shared__ float sX[CDIM * 68];
    const int b  = blockIdx.y;
    const int p0 = blockIdx.x * 64;
    const int tid = threadIdx.x;

#pragma unroll
    for (int i = 0; i < 12; ++i) {
        const int idx = tid + i * 256;        // 0..3071 float4s
        const int p4 = idx & 15, k = idx >> 4;
        const float4 v = *reinterpret_cast<const float4*>(
            X + ((size_t)b * CDIM + k) * HWPIX + p0 + p4 * 4);
        *reinterpret_cast<float4*>(&sX[k * 68 + p4 * 4]) = v;
    }
    __syncthreads();

    const int p = tid >> 2;          // 0..63
    const int seg = tid & 3;         // 0..3 (6 k-blocks each)
    u16* dst = Xt + ((size_t)b * HWPIX + p0 + p) * CDIM;
#pragma unroll
    for (int s = 0; s < 6; ++s) {
        const int blk = seg * 6 + s; // 0..23, 8 k each
        float f[8];
#pragma unroll
        for (int j = 0; j < 8; ++j) f[j] = sX[(blk * 8 + j) * 68 + p];
        uint4 ov;
        ov.x = pack2(f[0], f[1]);
        ov.y = pack2(f[2], f[3]);
        ov.z = pack2(f[4], f[5]);
        ov.w = pack2(f[6], f[7]);
        *reinterpret_cast<uint4*>(dst + blk * 8) = ov;
    }
}

// ---------------------------------------------------------------------------
// Shared MFMA inner block (R10 proven structure).
// ---------------------------------------------------------------------------
__device__ __forceinline__ void chunk_mfma(
    const u16* sA, const u16* sB, int r, int hk, int wave, f32x4 (&acc)[4][2])
{
#pragma unroll
    for (int ks = 0; ks < 3; ++ks) {
        const int kof = ks * 32 + hk * 8;
        const u16* pA = &sA[r * KP + kof];
        const u16* pB = &sB[(wave * 32 + r) * KP + kof];
        const short8 a0 = *reinterpret_cast<const short8*>(pA);
        const short8 a1 = *reinterpret_cast<const short8*>(pA + 16 * KP);
        const short8 a2 = *reinterpret_cast<const short8*>(pA + 32 * KP);
        const short8 a3 = *reinterpret_cast<const short8*>(pA + 48 * KP);
        const short8 b0 = *reinterpret_cast<const short8*>(pB);
        const short8 b1 = *reinterpret_cast<const short8*>(pB + 16 * KP);
        acc[0][0] = __builtin_amdgcn_mfma_f32_16x16x32_bf16(a0, b0, acc[0][0], 0, 0, 0);
        acc[1][0] = __builtin_amdgcn_mfma_f32_16x16x32_bf16(a1, b0, acc[1][0], 0, 0, 0);
        acc[2][0] = __builtin_amdgcn_mfma_f32_16x16x32_bf16(a2, b0, acc[2][0], 0, 0, 0);
        acc[3][0] = __builtin_amdgcn_mfma_f32_16x16x32_bf16(a3, b0, acc[3][0], 0, 0, 0);
        acc[0][1] = __builtin_amdgcn_mfma_f32_16x16x32_bf16(a0, b1, acc[0][1], 0, 0, 0);
        acc[1][1] = __builtin_amdgcn_mfma_f32_16x16x32_bf16(a1, b1, acc[1][1], 0, 0, 0);
        acc[2][1] = __builtin_amdgcn_mfma_f32_16x16x32_bf16(a2, b1, acc[2][1], 0, 0, 0);
        acc[3][1] = __builtin_amdgcn_mfma_f32_16x16x32_bf16(a3, b1, acc[3][1], 0, 0, 0);
    }
}

// ---------------------------------------------------------------------------
// qkv 1x1 conv (exact R10 structure, frozen): Y bf16 [b][co][p].
// ---------------------------------------------------------------------------
__global__ __launch_bounds__(256, 4) void conv_qkv_mfma(
    const u16* __restrict__ Xt, const u16* __restrict__ Wb,
    const float* __restrict__ bias, bf16* __restrict__ Y)
{
    __shared__ alignas(16) u16 sA[64 * KP];
    __shared__ alignas(16) u16 sB[128 * KP];
    __shared__ float sBias[64];

    int lin = blockIdx.x;
    lin = (lin & 7) * (18432 / 8) + (lin >> 3);
    const int co_t = lin % 9;
    const int rest = lin / 9;
    const int p_t = rest & 511;
    const int b   = rest >> 9;
    const int co0 = co_t * 64;
    const int p0  = p_t * 128;

    const int tid  = threadIdx.x;
    const int wave = tid >> 6;
    const int lane = tid & 63;
    const int r  = lane & 15;
    const int hk = lane >> 4;

    if (tid < 64) sBias[tid] = bias[co0 + tid];

    f32x4 acc[4][2];
#pragma unroll
    for (int i = 0; i < 4; ++i)
#pragma unroll
        for (int j = 0; j < 2; ++j) acc[i][j] = (f32x4){0.f, 0.f, 0.f, 0.f};

#pragma unroll
    for (int c = 0; c < 2; ++c) {
        {
            int idx = tid;
#pragma unroll
            for (int i = 0; i < 3; ++i, idx += 256) {
                const int row = idx / 12, cv = idx % 12;
                const uint4 v = *reinterpret_cast<const uint4*>(
                    Wb + (size_t)(co0 + row) * CDIM + c * 96 + cv * 8);
                *reinterpret_cast<uint4*>(&sA[row * KP + cv * 8]) = v;
            }
        }
        {
            int idx = tid;
#pragma unroll
            for (int i = 0; i < 6; ++i, idx += 256) {
                const int row = idx / 12, cv = idx % 12;
                const uint4 v = *reinterpret_cast<const uint4*>(
                    Xt + ((size_t)b * HWPIX + p0 + row) * CDIM + c * 96 + cv * 8);
                *reinterpret_cast<uint4*>(&sB[row * KP + cv * 8]) = v;
            }
        }
        __syncthreads();
        chunk_mfma(sA, sB, r, hk, wave, acc);
        __syncthreads();
    }

#define OS2 132
    u16* sOut = sB;
#pragma unroll
    for (int mf = 0; mf < 4; ++mf) {
#pragma unroll
        for (int j = 0; j < 4; ++j) {
            const int row = mf * 16 + hk * 4 + j;
            const float bs = sBias[row];
            sOut[row * OS2 + wave * 32 + r]      = f2bu(acc[mf][0][j] + bs);
            sOut[row * OS2 + wave * 32 + r + 16] = f2bu(acc[mf][1][j] + bs);
        }
    }
    __syncthreads();
#pragma unroll
    for (int i = 0; i < 4; ++i) {
        const int idx = tid + i * 256;
        const int row = idx >> 4, cq = idx & 15;
        const u16* src = &sOut[row * OS2 + cq * 8];
        const uint2 lo = *reinterpret_cast<const uint2*>(src);
        const uint2 hi = *reinterpret_cast<const uint2*>(src + 4);
        uint4 v = {lo.x, lo.y, hi.x, hi.y};
        *reinterpret_cast<uint4*>(
            &Y[((size_t)b * C3 + co0 + row) * HWPIX + p0 + cq * 8]) = v;
    }
}

// ---------------------------------------------------------------------------
// proj 1x1 conv — reads head-grouped Ot [b][head][p][24] bf16 (pure copy
// staging), f32 out. (R14 version, unchanged.)
// ---------------------------------------------------------------------------
__global__ __launch_bounds__(256, 4) void conv_proj_mfma(
    const u16* __restrict__ Ot, const u16* __restrict__ Wb,
    const float* __restrict__ bias, float* __restrict__ Y)
{
    __shared__ alignas(16) u16 sA[64 * KP];
    __shared__ alignas(16) u16 sB[128 * KP];
    __shared__ float sBias[64];

    int lin = blockIdx.x;                       // nwg = 6144
    lin = (lin & 7) * (6144 / 8) + (lin >> 3);
    const int co_t = lin % 3;
    const int rest = lin / 3;
    const int p_t = rest & 511;
    const int b   = rest >> 9;
    const int co0 = co_t * 64;
    const int p0  = p_t * 128;

    const int tid  = threadIdx.x;
    const int wave = tid >> 6;
    const int lane = tid & 63;
    const int r  = lane & 15;
    const int hk = lane >> 4;

    if (tid < 64) sBias[tid] = bias[co0 + tid];

    f32x4 acc[4][2];
#pragma unroll
    for (int i = 0; i < 4; ++i)
#pragma unroll
        for (int j = 0; j < 2; ++j) acc[i][j] = (f32x4){0.f, 0.f, 0.f, 0.f};

#pragma unroll
    for (int c = 0; c < 2; ++c) {
        {
            int idx = tid;
#pragma unroll
            for (int i = 0; i < 3; ++i, idx += 256) {
                const int row = idx / 12, cv = idx % 12;
                const uint4 v = *reinterpret_cast<const uint4*>(
                    Wb + (size_t)(co0 + row) * CDIM + c * 96 + cv * 8);
                *reinterpret_cast<uint4*>(&sA[row * KP + cv * 8]) = v;
            }
        }
        {
            int idx = tid;
#pragma unroll
            for (int i = 0; i < 6; ++i, idx += 256) {
                const int row = idx / 12, sub = idx % 12;
                const int h = c * 4 + sub / 3, part = sub % 3;
                const uint4 v = *reinterpret_cast<const uint4*>(
                    Ot + ((size_t)(b * NHEADS + h) * HWPIX + p0 + row) * CPH + part * 8);
                *reinterpret_cast<uint4*>(
                    &sB[row * KP + (sub / 3) * 24 + part * 8]) = v;
            }
        }
        __syncthreads();
        chunk_mfma(sA, sB, r, hk, wave, acc);
        __syncthreads();
    }

#pragma unroll
    for (int mf = 0; mf < 4; ++mf) {
#pragma unroll
        for (int j = 0; j < 4; ++j) {
            const int co = co0 + mf * 16 + hk * 4 + j;
            const float bs = sBias[mf * 16 + hk * 4 + j];
            const size_t base = ((size_t)b * CDIM + co) * HWPIX + p0 + wave * 32 + r;
            Y[base]      = acc[mf][0][j] + bs;
            Y[base + 16] = acc[mf][1][j] + bs;
        }
    }
}

// ---------------------------------------------------------------------------
// Depthwise 3x3 SAME conv — 32-row tiles (unchanged).
// ---------------------------------------------------------------------------
__global__ __launch_bounds__(256) void dwconv_kernel(
    const bf16* __restrict__ In, const float* __restrict__ Wd,
    const float* __restrict__ bd, bf16* __restrict__ Out)
{
    __shared__ alignas(16) u16 sIn[34 * 256];   // 17408 B
    const int bc = blockIdx.y;            // b*576 + c
    const int c = bc % C3;
    const size_t base = (size_t)bc * HWPIX;
    const int r0 = blockIdx.x * 32;
    const int tid = threadIdx.x;

    for (int idx = tid; idx < 34 * 32; idx += 256) {
        const int lr = idx >> 5, ch = idx & 31;
        const int gr = r0 + lr - 1;
        uint4 v = {0u, 0u, 0u, 0u};
        if ((unsigned)gr < IMGW)
            v = *reinterpret_cast<const uint4*>(&In[base + (size_t)gr * IMGW + ch * 8]);
        *reinterpret_cast<uint4*>(&sIn[lr * 256 + ch * 8]) = v;
    }
    __syncthreads();

    float wg[9];
#pragma unroll
    for (int t = 0; t < 9; ++t) wg[t] = Wd[c * 9 + t];

    const int rr  = tid >> 5;             // 0..7
    const int px0 = (tid & 31) * 8;
    const float bias = bd[c];

#pragma unroll
    for (int kk = 0; kk < 4; ++kk) {
        const int orow = rr + kk * 8;     // output row within tile 0..31
        float acc[8];
#pragma unroll
        for (int j = 0; j < 8; ++j) acc[j] = bias;

#pragma unroll
        for (int dy = 0; dy < 3; ++dy) {
            const u16* rp = &sIn[(orow + dy) * 256];
            const short8 mv = *reinterpret_cast<const short8*>(&rp[px0]);
            float m[8];
#pragma unroll
            for (int j = 0; j < 8; ++j) m[j] = bu2f((u16)mv[j]);
            const float lft = (px0 > 0) ? bu2f(rp[px0 - 1]) : 0.f;
            const float rgt = (px0 + 8 < 256) ? bu2f(rp[px0 + 8]) : 0.f;
            const float w0 = wg[dy * 3], w1 = wg[dy * 3 + 1], w2 = wg[dy * 3 + 2];

            acc[0] = fmaf(w0, lft, acc[0]);
            acc[0] = fmaf(w1, m[0], acc[0]);
            acc[0] = fmaf(w2, m[1], acc[0]);
#pragma unroll
            for (int j = 1; j < 7; ++j) {
                acc[j] = fmaf(w0, m[j - 1], acc[j]);
                acc[j] = fmaf(w1, m[j], acc[j]);
                acc[j] = fmaf(w2, m[j + 1], acc[j]);
            }
            acc[7] = fmaf(w0, m[6], acc[7]);
            acc[7] = fmaf(w1, m[7], acc[7]);
            acc[7] = fmaf(w2, rgt, acc[7]);
        }

        uint4 ov;
        ov.x = pack2(acc[0], acc[1]);
        ov.y = pack2(acc[2], acc[3]);
        ov.z = pack2(acc[4], acc[5]);
        ov.w = pack2(acc[6], acc[7]);
        *reinterpret_cast<uint4*>(&Out[base + (size_t)(r0 + orow) * IMGW + px0]) = ov;
    }
}

// ---------------------------------------------------------------------------
// Local (windowed 8x8) channel attention + fused global apply.
// R15: LDS diet for 4 blocks/CU — stage only Q,K up front (2x24xCS arena);
// after Gram barrier: V overlays sQ (T14 reg-split: loads issued before
// softmax, ds_write after), sP overlays sK; sO later overlays sP (extra
// barrier after PV since sP/sO share the sK region).
// ---------------------------------------------------------------------------
#define CS 328          // c-row stride (u16)
#define PS 40           // row stride (u16) for sP
#define OS3 28          // pixel-major out tile stride (u16)

__global__ __launch_bounds__(256, 4) void local_attn_kernel(
    const bf16* __restrict__ QKV, const float* __restrict__ temp,
    const float* __restrict__ Ag, u16* __restrict__ Ot)
{
    __shared__ alignas(16) u16 sMem[2 * 24 * CS];
    __shared__ float snq[4 * 32], snk[4 * 32];
    __shared__ float sAg[576];
    u16* const sQ = sMem;
    u16* const sK = sMem + 24 * CS;
    u16* const sV = sMem;            // overlay: sQ dead after Gram
    u16* const sP = sMem + 24 * CS;  // overlay: sK dead after Gram (5120<=7872)
    u16* const sO = sMem + 24 * CS;  // overlay: sP dead after afr+barrier (7168<=7872)

    const int wy    = blockIdx.x >> 3;
    const int strip = blockIdx.x & 7;
    const int head  = blockIdx.y;
    const int b     = blockIdx.z;
    const int x0    = strip * 32;
    const int tid   = threadIdx.x;
    const int w     = tid >> 6;
    const int lane  = tid & 63;
    const int r     = lane & 15;
    const int hk    = lane >> 4;

    {
        const float* Asrc = Ag + ((size_t)(b * NHEADS + head)) * 576;
        for (int idx = tid; idx < 576; idx += 256) sAg[idx] = Asrc[idx];
    }

    // ---- stage Q,K only (6 uint4/thread)
#pragma unroll
    for (int i = 0; i < 6; ++i) {
        const int idx = tid + i * 256;       // 0..1535
        const int tensor = idx / 768;        // 0 or 1
        const int rem = idx - tensor * 768;
        const int c  = rem >> 5;
        const int rw = (rem >> 2) & 7;
        const int ch = rem & 3;
        const size_t g = ((size_t)b * C3 + tensor * CDIM + head * CPH + c) * HWPIX
                       + (size_t)(wy * 8 + rw) * IMGW + x0 + ch * 8;
        const uint4 v = *reinterpret_cast<const uint4*>(&QKV[g]);
        u16* dst = sMem + tensor * (24 * CS);
        *reinterpret_cast<uint4*>(&dst[c * CS + rw * 40 + ch * 8]) = v;
    }
    __syncthreads();

    // ---- per-window q,k inverse norms
    if (tid < 192) {
        const int qk = tid / 96;
        const int rem = tid - qk * 96;
        const int ww = rem / 24, c = rem % 24;
        const u16* sT = qk ? sK : sQ;
        const int off = c * CS + ww * 8;
        float s = 0.f;
#pragma unroll
        for (int rw = 0; rw < 8; ++rw) {
            const int rw2 = (rw + c) & 7;
            const short8 v = *reinterpret_cast<const short8*>(&sT[off + rw2 * 40]);
#pragma unroll
            for (int j = 0; j < 8; ++j) {
                const float f = bu2f((u16)v[j]);
                s = fmaf(f, f, s);
            }
        }
        const float inv = 1.f / fmaxf(sqrtf(s), 1e-12f);
        if (qk) snk[ww * 32 + c] = inv; else snq[ww * 32 + c] = inv;
    }
    __syncthreads();

    // ---- Gram MFMA
    f32x4 accg[2][2];
#pragma unroll
    for (int i = 0; i < 2; ++i)
#pragma unroll
        for (int j = 0; j < 2; ++j) accg[i][j] = (f32x4){0.f, 0.f, 0.f, 0.f};

    __builtin_amdgcn_s_setprio(1);
#pragma unroll
    for (int kk = 0; kk < 2; ++kk) {
        const int colA = (kk * 4 + hk) * 40 + w * 8;
        const short8 aq0 = *reinterpret_cast<const short8*>(&sQ[(r     ) * CS + colA]);
        const short8 aq1 = *reinterpret_cast<const short8*>(&sQ[(16 + r) * CS + colA]);
        const short8 bk0 = *reinterpret_cast<const short8*>(&sK[(r     ) * CS + colA]);
        const short8 bk1 = *reinterpret_cast<const short8*>(&sK[(16 + r) * CS + colA]);
        accg[0][0] = __builtin_amdgcn_mfma_f32_16x16x32_bf16(aq0, bk0, accg[0][0], 0, 0, 0);
        accg[0][1] = __builtin_amdgcn_mfma_f32_16x16x32_bf16(aq0, bk1, accg[0][1], 0, 0, 0);
        accg[1][0] = __builtin_amdgcn_mfma_f32_16x16x32_bf16(aq1, bk0, accg[1][0], 0, 0, 0);
        accg[1][1] = __builtin_amdgcn_mfma_f32_16x16x32_bf16(aq1, bk1, accg[1][1], 0, 0, 0);
    }
    __builtin_amdgcn_s_setprio(0);
    __syncthreads();   // Gram reads done -> sQ,sK reusable

    // ---- T14: issue V global loads now (latency hides under softmax VALU)
    uint4 vr0, vr1, vr2;
    int vl0, vl1, vl2;
    {
        const int idx0 = tid;
        const int c0 = idx0 >> 5, rw0 = (idx0 >> 2) & 7, ch0 = idx0 & 3;
        vr0 = *reinterpret_cast<const uint4*>(&QKV[
            ((size_t)b * C3 + 2 * CDIM + head * CPH + c0) * HWPIX
            + (size_t)(wy * 8 + rw0) * IMGW + x0 + ch0 * 8]);
        vl0 = c0 * CS + rw0 * 40 + ch0 * 8;
        const int idx1 = tid + 256;
        const int c1 = idx1 >> 5, rw1 = (idx1 >> 2) & 7, ch1 = idx1 & 3;
        vr1 = *reinterpret_cast<const uint4*>(&QKV[
            ((size_t)b * C3 + 2 * CDIM + head * CPH + c1) * HWPIX
            + (size_t)(wy * 8 + rw1) * IMGW + x0 + ch1 * 8]);
        vl1 = c1 * CS + rw1 * 40 + ch1 * 8;
        const int idx2 = tid + 512;
        const int c2 = idx2 >> 5, rw2 = (idx2 >> 2) & 7, ch2 = idx2 & 3;
        vr2 = *reinterpret_cast<const uint4*>(&QKV[
            ((size_t)b * C3 + 2 * CDIM + head * CPH + c2) * HWPIX
            + (size_t)(wy * 8 + rw2) * IMGW + x0 + ch2 * 8]);
        vl2 = c2 * CS + rw2 * 40 + ch2 * 8;
    }

    // ---- softmax (+ global-A add) -> sP bf16
    const float t = temp[head];
    const int e0 = lane & 15;
    const bool v1 = e0 < 8;
    const float ink0 = snk[w * 32 + e0];
    const float ink1 = snk[w * 32 + 16 + e0];

#pragma unroll
    for (int ct = 0; ct < 2; ++ct) {
#pragma unroll
        for (int j = 0; j < 4; ++j) {
            const int cidx = ct * 16 + hk * 4 + j;
            const float inq = snq[w * 32 + (cidx < CPH ? cidx : 0)];
            const float g0 = accg[ct][0][j] * inq * ink0 * t;
            const float g1 = v1 ? accg[ct][1][j] * inq * ink1 * t : -1e30f;
            float m = fmaxf(g0, g1);
#pragma unroll
            for (int mk = 8; mk >= 1; mk >>= 1) m = fmaxf(m, __shfl_xor(m, mk));
            const float p0 = __expf(g0 - m);
            const float p1 = v1 ? __expf(g1 - m) : 0.f;
            float s = p0 + p1;
#pragma unroll
            for (int mk = 8; mk >= 1; mk >>= 1) s += __shfl_xor(s, mk);
            const float inv = 1.f / s;
            if (cidx < CPH) {
                sP[w * 32 * PS + cidx * PS + e0] = f2bu(p0 * inv + sAg[cidx * CPH + e0]);
                if (v1) sP[w * 32 * PS + cidx * PS + 16 + e0]
                    = f2bu(p1 * inv + sAg[cidx * CPH + 16 + e0]);
            }
        }
    }

    // ---- write V regs into LDS (sV overlays sQ)
    *reinterpret_cast<uint4*>(&sV[vl0]) = vr0;
    *reinterpret_cast<uint4*>(&sV[vl1]) = vr1;
    *reinterpret_cast<uint4*>(&sV[vl2]) = vr2;
    __syncthreads();

    // ---- PV MFMA
    f32x4 acco[2][4];
#pragma unroll
    for (int i = 0; i < 2; ++i)
#pragma unroll
        for (int j = 0; j < 4; ++j) acco[i][j] = (f32x4){0.f, 0.f, 0.f, 0.f};

    short8 afr[2];
#pragma unroll
    for (int ct = 0; ct < 2; ++ct) {
        if (hk < 3)
            afr[ct] = *reinterpret_cast<const short8*>(
                &sP[w * 32 * PS + (ct * 16 + r) * PS + hk * 8]);
        else
            afr[ct] = (short8){0, 0, 0, 0, 0, 0, 0, 0};
    }
    __builtin_amdgcn_s_setprio(1);
#pragma unroll
    for (int nt = 0; nt < 4; ++nt) {
        const int px = nt * 16 + r;
        const int colV = (px >> 3) * 40 + w * 8 + (px & 7);
        short8 bfr;
        if (hk < 3) {
#pragma unroll
            for (int j = 0; j < 8; ++j)
                bfr[j] = (short)sV[(hk * 8 + j) * CS + colV];
        } else {
            bfr = (short8){0, 0, 0, 0, 0, 0, 0, 0};
        }
        acco[0][nt] = __builtin_amdgcn_mfma_f32_16x16x32_bf16(afr[0], bfr, acco[0][nt], 0, 0, 0);
        acco[1][nt] = __builtin_amdgcn_mfma_f32_16x16x32_bf16(afr[1], bfr, acco[1][nt], 0, 0, 0);
    }
    __builtin_amdgcn_s_setprio(0);
    __syncthreads();   // all sP reads (afr) + sV reads done before sO overlay

    // ---- epilogue: pixel-major LDS tile, then 48B-contiguous stores into
    // Ot[b][head][p][24] (1536B contiguous per block-row).
#pragma unroll
    for (int ct = 0; ct < 2; ++ct) {
#pragma unroll
        for (int j = 0; j < 4; ++j) {
            const int cidx = ct * 16 + hk * 4 + j;
            if (cidx >= CPH) continue;
#pragma unroll
            for (int nt = 0; nt < 4; ++nt) {
                const int px = nt * 16 + r;
                const int rpx = px >> 3, pxl = px & 7;
                const int lp = rpx * 32 + w * 8 + pxl;   // 0..255
                sO[lp * OS3 + cidx] = f2bu(acco[ct][nt][j]);
            }
        }
    }
    __syncthreads();

    {
        const int lp = tid;                      // one pixel per thread
        const int gp = (wy * 8 + (lp >> 5)) * IMGW + x0 + (lp & 31);
        const u16* src = &sO[lp * OS3];
        uint2 d0 = *reinterpret_cast<const uint2*>(src);
        uint2 d1 = *reinterpret_cast<const uint2*>(src + 4);
        uint2 d2 = *reinterpret_cast<const uint2*>(src + 8);
        uint2 d3 = *reinterpret_cast<const uint2*>(src + 12);
        uint2 d4 = *reinterpret_cast<const uint2*>(src + 16);
        uint2 d5 = *reinterpret_cast<const uint2*>(src + 20);
        u16* dst = Ot + ((size_t)(b * NHEADS + head) * HWPIX + gp) * CPH;
        uint4 v0 = {d0.x, d0.y, d1.x, d1.y};
        uint4 v1 = {d2.x, d2.y, d3.x, d3.y};
        uint4 v2 = {d4.x, d4.y, d5.x, d5.y};
        *reinterpret_cast<uint4*>(dst)      = v0;
        *reinterpret_cast<uint4*>(dst + 8)  = v1;
        *reinterpret_cast<uint4*>(dst + 16) = v2;
    }
}

// ---------------------------------------------------------------------------
// Global branch stats — MFMA (unchanged).
// ---------------------------------------------------------------------------
#define GRS 520

__global__ __launch_bounds__(256) void gstats_kernel(
    const bf16* __restrict__ QKV, float* __restrict__ Gp)
{
    __shared__ alignas(16) u16 sq[32 * GRS];
    __shared__ alignas(16) u16 sk[32 * GRS];

    const int chunk = blockIdx.x;        // 0..15
    const int bh = blockIdx.y;           // 0..31
    const int b = bh >> 3, head = bh & 7;
    const int tid = threadIdx.x;
    const int w = tid >> 6, lane = tid & 63;
    const int r = lane & 15, hk = lane >> 4;

    const size_t qb = ((size_t)b * C3 + head * CPH) * HWPIX;
    const size_t kb = qb + (size_t)CDIM * HWPIX;

    for (int idx = tid; idx < 1040; idx += 256) {
        const int t = idx >= 520;
        const int o = idx - t * 520;
        u16* d = (t ? sk : sq) + 24 * GRS + o * 8;
        *reinterpret_cast<uint4*>(d) = (uint4){0u, 0u, 0u, 0u};
    }

    f32x4 acc[2][2];
#pragma unroll
    for (int i = 0; i < 2; ++i)
#pragma unroll
        for (int j = 0; j < 2; ++j) acc[i][j] = (f32x4){0.f, 0.f, 0.f, 0.f};
    float nacc = 0.f;
    const int nrow = tid >> 2;
    const int nq4  = tid & 3;

    for (int st = 0; st < 8; ++st) {
        const int d0 = chunk * 4096 + st * 512;
        __syncthreads();
#pragma unroll
        for (int i = 0; i < 12; ++i) {
            const int idx = tid + i * 256;
            const int t = idx >= 1536;
            const int rem = idx - t * 1536;
            const int c = rem >> 6, dv = rem & 63;
            const uint4 v = *reinterpret_cast<const uint4*>(
                &QKV[(t ? kb : qb) + (size_t)c * HWPIX + d0 + dv * 8]);
            u16* dst = (t ? sk : sq) + c * GRS + dv * 8;
            *reinterpret_cast<uint4*>(dst) = v;
        }
        __syncthreads();

#pragma unroll
        for (int ks = 0; ks < 4; ++ks) {
            const int kof = w * 128 + ks * 32 + hk * 8;
            const short8 aq0 = *reinterpret_cast<const short8*>(&sq[(r     ) * GRS + kof]);
            const short8 aq1 = *reinterpret_cast<const short8*>(&sq[(16 + r) * GRS + kof]);
            const short8 bk0 = *reinterpret_cast<const short8*>(&sk[(r     ) * GRS + kof]);
            const short8 bk1 = *reinterpret_cast<const short8*>(&sk[(16 + r) * GRS + kof]);
            acc[0][0] = __builtin_amdgcn_mfma_f32_16x16x32_bf16(aq0, bk0, acc[0][0], 0, 0, 0);
            acc[0][1] = __builtin_amdgcn_mfma_f32_16x16x32_bf16(aq0, bk1, acc[0][1], 0, 0, 0);
            acc[1][0] = __builtin_amdgcn_mfma_f32_16x16x32_bf16(aq1, bk0, acc[1][0], 0, 0, 0);
            acc[1][1] = __builtin_amdgcn_mfma_f32_16x16x32_bf16(aq1, bk1, acc[1][1], 0, 0, 0);
        }

        if (nrow < 48) {
            const u16* rp = (nrow < 24 ? &sq[nrow * GRS] : &sk[(nrow - 24) * GRS]) + nq4 * 128;
#pragma unroll
            for (int i = 0; i < 16; ++i) {
                const short8 v = *reinterpret_cast<const short8*>(&rp[i * 8]);
#pragma unroll
                for (int j = 0; j < 8; ++j) {
                    const float f = bu2f((u16)v[j]);
                    nacc = fmaf(f, f, nacc);
                }
            }
        }
    }
    __syncthreads();

    float* red = reinterpret_cast<float*>(sq);
#pragma unroll
    for (int ct = 0; ct < 2; ++ct) {
#pragma unroll
        for (int et = 0; et < 2; ++et) {
#pragma unroll
            for (int j = 0; j < 4; ++j) {
                const int c = ct * 16 + hk * 4 + j;
                const int e = et * 16 + r;
                if (c < CPH && e < CPH)
                    red[(w * 24 + c) * 25 + e] = acc[ct][et][j];
            }
        }
    }
    __syncthreads();

    float* dst = Gp + ((size_t)bh * 32 + chunk) * 624;
    for (int idx = tid; idx < 576; idx += 256) {
        const int c = idx / 24, e = idx % 24;
        const int o = c * 25 + e;
        dst[idx] = red[o] + red[600 + o] + red[1200 + o] + red[1800 + o];
    }

    float ns = nacc;
    ns += __shfl_xor(ns, 1);
    ns += __shfl_xor(ns, 2);
    if (nrow < 48 && nq4 == 0) {
        if (nrow < 24) dst[576 + nrow] = ns;
        else           dst[600 + (nrow - 24)] = ns;
    }
}

// ---------------------------------------------------------------------------
__global__ __launch_bounds__(64) void gsoftmax_kernel(
    const float* __restrict__ Gp, const float* __restrict__ temp,
    float* __restrict__ A)
{
    __shared__ float red[624];
    const int bh = blockIdx.x, head = bh & 7;
    const int tid = threadIdx.x;

    for (int jj = tid; jj < 624; jj += 64) {
        float s = 0.f;
        for (int ch = 0; ch < 16; ++ch) s += Gp[((size_t)bh * 32 + ch) * 624 + jj];
        red[jj] = s;
    }
    __syncthreads();

    if (tid < CPH) {
        const int c = tid;
        const float t = temp[head];
        const float inq = 1.f / fmaxf(sqrtf(red[576 + c]), 1e-12f);
        float l[CPH]; float m = -1e30f;
        for (int e = 0; e < CPH; ++e) {
            const float ink = 1.f / fmaxf(sqrtf(red[600 + e]), 1e-12f);
            l[e] = red[c * CPH + e] * inq * ink * t;
            m = fmaxf(m, l[e]);
        }
        float s = 0.f;
        for (int e = 0; e < CPH; ++e) { l[e] = expf(l[e] - m); s += l[e]; }
        const float inv = 1.f / s;
        for (int e = 0; e < CPH; ++e) A[(size_t)bh * 576 + c * CPH + e] = l[e] * inv;
    }
}

// ---------------------------------------------------------------------------
extern "C" void kernel_launch(void* const* d_in, const int* in_sizes, int n_in,
                              void* d_out, int out_size, void* d_ws, size_t ws_size,
                              hipStream_t stream) {
    const float* x           = (const float*)d_in[0];
    const float* temperature = (const float*)d_in[1];
    const float* qkv_w       = (const float*)d_in[2];
    const float* qkv_b       = (const float*)d_in[3];
    const float* dw_w        = (const float*)d_in[4];
    const float* dw_b        = (const float*)d_in[5];
    const float* proj_w      = (const float*)d_in[6];
    const float* proj_b      = (const float*)d_in[7];
    float* out = (float*)d_out;

    char* ws = (char*)d_ws;
    constexpr size_t QKV_ELEMS = (size_t)NBATCH * C3 * HWPIX;
    constexpr size_t QKV_BYTES = QKV_ELEMS * sizeof(bf16);

    bf16* qkv1 = (bf16*)ws;                       // conv1x1 out (bf16) [c][p]
    bf16* qkv2 = (bf16*)(ws + QKV_BYTES);         // q,k,v after depthwise
    u16*  osumT = (u16*)ws;                       // o1+o2 bf16 [b][head][p][24]
    float* Gp   = (float*)(ws + 2 * QKV_BYTES);   // partials
    float* Amat = Gp + (size_t)32 * 32 * 624;
    u16*  Wb    = (u16*)Gp;                       // qkv weights bf16 (dead before gstats)
    u16*  Wpb   = (u16*)(Amat + 32 * 576);        // proj weights bf16
    u16*  Xt    = (u16*)qkv2;                     // Xt overlays qkv2 (dead after conv_qkv)

    // 0. weights f32 -> bf16 (single launch for both tensors)
    prep_weights2<<<(C3 * CDIM + CDIM * CDIM + 255) / 256, 256, 0, stream>>>(
        qkv_w, Wb, C3 * CDIM, proj_w, Wpb, CDIM * CDIM);

    // 0b. X transpose+convert -> Xt
    xprep_kernel<<<dim3(HWPIX / 64, NBATCH), 256, 0, stream>>>(x, Xt);

    // 1. qkv = 1x1 conv via MFMA (R10 proven structure)
    conv_qkv_mfma<<<9 * 512 * NBATCH, 256, 0, stream>>>(Xt, Wb, qkv_b, qkv1);

    // 2. depthwise 3x3, 32-row tiles (overwrites Xt region — Xt dead)
    dwconv_kernel<<<dim3(8, NBATCH * C3), 256, 0, stream>>>(
        qkv1, dw_w, dw_b, qkv2);

    // 3. global Gram/norm partials via MFMA (overwrites Wb — dead)
    gstats_kernel<<<dim3(16, 32), 256, 0, stream>>>(qkv2, Gp);

    // 4. reduce + softmax -> A
    gsoftmax_kernel<<<32, 64, 0, stream>>>(Gp, temperature, Amat);

    // 5. local attention + fused global apply -> osumT [b][head][p][24]
    local_attn_kernel<<<dim3(256, NHEADS, NBATCH), 256, 0, stream>>>(
        qkv2, temperature, Amat, osumT);

    // 6. proj 1x1 conv via MFMA (head-grouped bf16 in, f32 out)
    conv_proj_mfma<<<3 * 512 * NBATCH, 256, 0, stream>>>(osumT, Wpb, proj_b, out);
}